// Round 1
// baseline (1427.850 us; speedup 1.0000x reference)
//
#include <hip/hip_runtime.h>
#include <math.h>

// Problem: B=32, M=1024, D=768, H=256, fp32 throughout.
// Pipeline:
//  g    = mean_m V                      [B,D]
//  gW   = g @ WV_w^T                    [B,H]
//  Vp   = alpha*(V@WV_w^T) + (1-a)*gW + WV_b   [B,M,H]
//  res  = V@res_w^T + res_b             [B,M,H]   (fused with Vp GEMM, K=768, N=512)
//  S    = Vp @ Vp^T                     [B,M,M]
//  S    = softmax_rows(S)
//  t1   = S^T @ Vp                      [B,M,H]
//  t2   = t1 @ W_conv                   [B,M,H]
//  out  = relu(S @ t2 + res)            [B,M,H]
// Workspace: ~224 MB fp32 (S is 128 MB; t2 aliases Vp).

#define TK 16

__device__ __forceinline__ void mac16(float acc[4][4], const float4 a, const float4 b) {
    acc[0][0] += a.x*b.x; acc[0][1] += a.x*b.y; acc[0][2] += a.x*b.z; acc[0][3] += a.x*b.w;
    acc[1][0] += a.y*b.x; acc[1][1] += a.y*b.y; acc[1][2] += a.y*b.z; acc[1][3] += a.y*b.w;
    acc[2][0] += a.z*b.x; acc[2][1] += a.z*b.y; acc[2][2] += a.z*b.z; acc[2][3] += a.z*b.w;
    acc[3][0] += a.w*b.x; acc[3][1] += a.w*b.y; acc[3][2] += a.w*b.z; acc[3][3] += a.w*b.w;
}

// ---- k_mean: g[b,d] = mean over m of V[b,m,d].  grid 96x256 covers B*D=24576
__global__ __launch_bounds__(256) void k_mean(const float* __restrict__ V, float* __restrict__ g) {
    int idx = blockIdx.x * 256 + threadIdx.x;          // 768 = 3*256 -> uniform b per block
    int b = idx / 768, d = idx % 768;
    const float* p = V + (size_t)b * 1024 * 768 + d;
    float s = 0.f;
    for (int m = 0; m < 1024; ++m) s += p[(size_t)m * 768];
    g[idx] = s * (1.0f / 1024.0f);
}

// ---- k_gW: gW[b,h] = sum_d g[b,d]*WVw[h,d].  grid 32x256 covers B*H=8192
__global__ __launch_bounds__(256) void k_gW(const float* __restrict__ g,
                                            const float* __restrict__ WVw,
                                            float* __restrict__ gW) {
    int idx = blockIdx.x * 256 + threadIdx.x;
    int b = idx >> 8, h = idx & 255;
    const float* gr = g + b * 768;
    const float* wr = WVw + (size_t)h * 768;
    float s = 0.f;
    for (int d = 0; d < 768; ++d) s += gr[d] * wr[d];
    gW[idx] = s;
}

// ---- k_proj: fused GEMM [32768 x 512] = V[32768x768] @ concat(WVw,resw)^T, epilogues split.
// grid (8, 512), block 256
__global__ __launch_bounds__(256) void k_proj(const float* __restrict__ V,
                                              const float* __restrict__ WVw,
                                              const float* __restrict__ WVb,
                                              const float* __restrict__ resw,
                                              const float* __restrict__ resb,
                                              const float* __restrict__ gW,
                                              const float* __restrict__ alpha_p,
                                              float* __restrict__ Vp,
                                              float* __restrict__ resv) {
    __shared__ float As[TK][64];
    __shared__ float Bs[TK][64];
    const int tid = threadIdx.x;
    const int tx = tid & 15, ty = tid >> 4;
    const int n0 = blockIdx.x * 64;
    const int r0 = blockIdx.y * 64;
    const int ar = tid >> 2;          // 0..63
    const int ac = (tid & 3) << 2;    // 0,4,8,12
    const int n = n0 + ar;
    const float* wrow = (n < 256) ? (WVw + (size_t)n * 768) : (resw + (size_t)(n - 256) * 768);
    const float* arow = V + (size_t)(r0 + ar) * 768;
    float acc[4][4] = {};
    for (int k0 = 0; k0 < 768; k0 += TK) {
        float4 av = *(const float4*)(arow + k0 + ac);
        float4 bv = *(const float4*)(wrow + k0 + ac);
        As[ac + 0][ar] = av.x; As[ac + 1][ar] = av.y; As[ac + 2][ar] = av.z; As[ac + 3][ar] = av.w;
        Bs[ac + 0][ar] = bv.x; Bs[ac + 1][ar] = bv.y; Bs[ac + 2][ar] = bv.z; Bs[ac + 3][ar] = bv.w;
        __syncthreads();
        #pragma unroll
        for (int kk = 0; kk < TK; ++kk)
            mac16(acc, *(const float4*)&As[kk][ty << 2], *(const float4*)&Bs[kk][tx << 2]);
        __syncthreads();
    }
    const float alpha = *alpha_p;
    const float oma = 1.0f - alpha;
    if (n0 < 256) {
        #pragma unroll
        for (int i = 0; i < 4; ++i) {
            int r = r0 + (ty << 2) + i;
            int bb = r >> 10;
            int nn = n0 + (tx << 2);
            float4 o;
            o.x = alpha * acc[i][0] + oma * gW[(bb << 8) + nn + 0] + WVb[nn + 0];
            o.y = alpha * acc[i][1] + oma * gW[(bb << 8) + nn + 1] + WVb[nn + 1];
            o.z = alpha * acc[i][2] + oma * gW[(bb << 8) + nn + 2] + WVb[nn + 2];
            o.w = alpha * acc[i][3] + oma * gW[(bb << 8) + nn + 3] + WVb[nn + 3];
            *(float4*)&Vp[(size_t)r * 256 + nn] = o;
        }
    } else {
        #pragma unroll
        for (int i = 0; i < 4; ++i) {
            int r = r0 + (ty << 2) + i;
            int nn = n0 - 256 + (tx << 2);
            float4 o;
            o.x = acc[i][0] + resb[nn + 0];
            o.y = acc[i][1] + resb[nn + 1];
            o.z = acc[i][2] + resb[nn + 2];
            o.w = acc[i][3] + resb[nn + 3];
            *(float4*)&resv[(size_t)r * 256 + nn] = o;
        }
    }
}

// ---- k_sim: S_b = Vp_b @ Vp_b^T.  grid (16,16,32)
__global__ __launch_bounds__(256) void k_sim(const float* __restrict__ Vp, float* __restrict__ S) {
    const int b = blockIdx.z;
    const float* A = Vp + (size_t)b * 1024 * 256;
    __shared__ float As[TK][64];
    __shared__ float Bs[TK][64];
    const int tid = threadIdx.x;
    const int tx = tid & 15, ty = tid >> 4;
    const int j0 = blockIdx.x * 64, i0 = blockIdx.y * 64;
    const int ar = tid >> 2;
    const int ac = (tid & 3) << 2;
    const float* arow = A + (size_t)(i0 + ar) * 256;
    const float* brow = A + (size_t)(j0 + ar) * 256;
    float acc[4][4] = {};
    for (int k0 = 0; k0 < 256; k0 += TK) {
        float4 av = *(const float4*)(arow + k0 + ac);
        float4 bv = *(const float4*)(brow + k0 + ac);
        As[ac + 0][ar] = av.x; As[ac + 1][ar] = av.y; As[ac + 2][ar] = av.z; As[ac + 3][ar] = av.w;
        Bs[ac + 0][ar] = bv.x; Bs[ac + 1][ar] = bv.y; Bs[ac + 2][ar] = bv.z; Bs[ac + 3][ar] = bv.w;
        __syncthreads();
        #pragma unroll
        for (int kk = 0; kk < TK; ++kk)
            mac16(acc, *(const float4*)&As[kk][ty << 2], *(const float4*)&Bs[kk][tx << 2]);
        __syncthreads();
    }
    float* Sb = S + (size_t)b * 1024 * 1024;
    #pragma unroll
    for (int i = 0; i < 4; ++i) {
        int r = i0 + (ty << 2) + i;
        *(float4*)&Sb[(size_t)r * 1024 + j0 + (tx << 2)] =
            make_float4(acc[i][0], acc[i][1], acc[i][2], acc[i][3]);
    }
}

// ---- k_softmax: in-place row softmax over 1024 cols. grid 32768 x 256
__global__ __launch_bounds__(256) void k_softmax(float* __restrict__ S) {
    const size_t row = blockIdx.x;
    float* p = S + row * 1024;
    const int tid = threadIdx.x;
    float4 v = *(const float4*)&p[tid * 4];
    float lm = fmaxf(fmaxf(v.x, v.y), fmaxf(v.z, v.w));
    #pragma unroll
    for (int o = 32; o > 0; o >>= 1) lm = fmaxf(lm, __shfl_xor(lm, o, 64));
    __shared__ float red[4];
    const int wid = tid >> 6, lane = tid & 63;
    if (lane == 0) red[wid] = lm;
    __syncthreads();
    const float m = fmaxf(fmaxf(red[0], red[1]), fmaxf(red[2], red[3]));
    __syncthreads();
    v.x = __expf(v.x - m); v.y = __expf(v.y - m); v.z = __expf(v.z - m); v.w = __expf(v.w - m);
    float ls = v.x + v.y + v.z + v.w;
    #pragma unroll
    for (int o = 32; o > 0; o >>= 1) ls += __shfl_xor(ls, o, 64);
    if (lane == 0) red[wid] = ls;
    __syncthreads();
    const float inv = 1.0f / (red[0] + red[1] + red[2] + red[3]);
    v.x *= inv; v.y *= inv; v.z *= inv; v.w *= inv;
    *(float4*)&p[tid * 4] = v;
}

// ---- k_t1: t1_b = S_b^T @ Vp_b  (t1[m,h] = sum_n S[n,m] Vp[n,h]).  grid (4,16,32)
__global__ __launch_bounds__(256) void k_t1(const float* __restrict__ S,
                                            const float* __restrict__ Vp,
                                            float* __restrict__ t1) {
    const int b = blockIdx.z;
    const float* Hm = S + (size_t)b * 1024 * 1024;
    const float* Bm = Vp + (size_t)b * 1024 * 256;
    __shared__ float As[TK][64];
    __shared__ float Bs[TK][64];
    const int tid = threadIdx.x;
    const int tx = tid & 15, ty = tid >> 4;
    const int h0 = blockIdx.x * 64, m0 = blockIdx.y * 64;
    const int lk = tid >> 4;          // 0..15
    const int lc = (tid & 15) << 2;   // 0..60
    float acc[4][4] = {};
    for (int k0 = 0; k0 < 1024; k0 += TK) {
        float4 av = *(const float4*)&Hm[(size_t)(k0 + lk) * 1024 + m0 + lc];
        float4 bv = *(const float4*)&Bm[(size_t)(k0 + lk) * 256 + h0 + lc];
        *(float4*)&As[lk][lc] = av;
        *(float4*)&Bs[lk][lc] = bv;
        __syncthreads();
        #pragma unroll
        for (int kk = 0; kk < TK; ++kk)
            mac16(acc, *(const float4*)&As[kk][ty << 2], *(const float4*)&Bs[kk][tx << 2]);
        __syncthreads();
    }
    float* out = t1 + (size_t)b * 1024 * 256;
    #pragma unroll
    for (int i = 0; i < 4; ++i) {
        int r = m0 + (ty << 2) + i;
        *(float4*)&out[(size_t)r * 256 + h0 + (tx << 2)] =
            make_float4(acc[i][0], acc[i][1], acc[i][2], acc[i][3]);
    }
}

// ---- k_t2: t2 = t1 @ W_conv.  [32768x256] @ [256x256]. grid (4,512)
__global__ __launch_bounds__(256) void k_t2(const float* __restrict__ t1,
                                            const float* __restrict__ Wc,
                                            float* __restrict__ t2) {
    __shared__ float As[TK][64];
    __shared__ float Bs[TK][64];
    const int tid = threadIdx.x;
    const int tx = tid & 15, ty = tid >> 4;
    const int n0 = blockIdx.x * 64;
    const int r0 = blockIdx.y * 64;
    const int ar = tid >> 2;
    const int ac = (tid & 3) << 2;
    const int lk = tid >> 4;
    const int lc = (tid & 15) << 2;
    const float* arow = t1 + (size_t)(r0 + ar) * 256;
    float acc[4][4] = {};
    for (int k0 = 0; k0 < 256; k0 += TK) {
        float4 av = *(const float4*)(arow + k0 + ac);
        float4 bv = *(const float4*)&Wc[(size_t)(k0 + lk) * 256 + n0 + lc];
        As[ac + 0][ar] = av.x; As[ac + 1][ar] = av.y; As[ac + 2][ar] = av.z; As[ac + 3][ar] = av.w;
        *(float4*)&Bs[lk][lc] = bv;
        __syncthreads();
        #pragma unroll
        for (int kk = 0; kk < TK; ++kk)
            mac16(acc, *(const float4*)&As[kk][ty << 2], *(const float4*)&Bs[kk][tx << 2]);
        __syncthreads();
    }
    #pragma unroll
    for (int i = 0; i < 4; ++i) {
        int r = r0 + (ty << 2) + i;
        *(float4*)&t2[(size_t)r * 256 + n0 + (tx << 2)] =
            make_float4(acc[i][0], acc[i][1], acc[i][2], acc[i][3]);
    }
}

// ---- k_O: out = relu(S_b @ t2_b + res).  grid (4,16,32)
__global__ __launch_bounds__(256) void k_O(const float* __restrict__ S,
                                           const float* __restrict__ t2,
                                           const float* __restrict__ resv,
                                           float* __restrict__ out) {
    const int b = blockIdx.z;
    const float* Am = S + (size_t)b * 1024 * 1024;
    const float* Bm = t2 + (size_t)b * 1024 * 256;
    __shared__ float As[TK][64];
    __shared__ float Bs[TK][64];
    const int tid = threadIdx.x;
    const int tx = tid & 15, ty = tid >> 4;
    const int h0 = blockIdx.x * 64, m0 = blockIdx.y * 64;
    const int ar = tid >> 2;
    const int ac = (tid & 3) << 2;
    const int lk = tid >> 4;
    const int lc = (tid & 15) << 2;
    const float* arow = Am + (size_t)(m0 + ar) * 1024;
    float acc[4][4] = {};
    for (int k0 = 0; k0 < 1024; k0 += TK) {
        float4 av = *(const float4*)(arow + k0 + ac);
        float4 bv = *(const float4*)&Bm[(size_t)(k0 + lk) * 256 + h0 + lc];
        As[ac + 0][ar] = av.x; As[ac + 1][ar] = av.y; As[ac + 2][ar] = av.z; As[ac + 3][ar] = av.w;
        *(float4*)&Bs[lk][lc] = bv;
        __syncthreads();
        #pragma unroll
        for (int kk = 0; kk < TK; ++kk)
            mac16(acc, *(const float4*)&As[kk][ty << 2], *(const float4*)&Bs[kk][tx << 2]);
        __syncthreads();
    }
    #pragma unroll
    for (int i = 0; i < 4; ++i) {
        int r = m0 + (ty << 2) + i;
        size_t off = ((size_t)b * 1024 + r) * 256 + h0 + (tx << 2);
        float4 rv = *(const float4*)&resv[off];
        float4 o;
        o.x = fmaxf(acc[i][0] + rv.x, 0.f);
        o.y = fmaxf(acc[i][1] + rv.y, 0.f);
        o.z = fmaxf(acc[i][2] + rv.z, 0.f);
        o.w = fmaxf(acc[i][3] + rv.w, 0.f);
        *(float4*)&out[off] = o;
    }
}

extern "C" void kernel_launch(void* const* d_in, const int* in_sizes, int n_in,
                              void* d_out, int out_size, void* d_ws, size_t ws_size,
                              hipStream_t stream) {
    const float* V     = (const float*)d_in[0];
    const float* alpha = (const float*)d_in[1];
    const float* WVw   = (const float*)d_in[2];
    const float* WVb   = (const float*)d_in[3];
    const float* Wc    = (const float*)d_in[4];
    const float* resw  = (const float*)d_in[5];
    const float* resb  = (const float*)d_in[6];
    float* out = (float*)d_out;

    // workspace carve-up (fp32): ~224 MB total
    float* g    = (float*)d_ws;           // 24576
    float* gW   = g + 24576;              // 8192
    float* Vp   = gW + 8192;              // 8,388,608
    float* resv = Vp + 8388608;           // 8,388,608
    float* t1   = resv + 8388608;         // 8,388,608
    float* t2   = Vp;                     // alias: Vp dead after k_t1
    float* S    = t1 + 8388608;           // 33,554,432

    k_mean<<<96, 256, 0, stream>>>(V, g);
    k_gW<<<32, 256, 0, stream>>>(g, WVw, gW);
    k_proj<<<dim3(8, 512), 256, 0, stream>>>(V, WVw, WVb, resw, resb, gW, alpha, Vp, resv);
    k_sim<<<dim3(16, 16, 32), 256, 0, stream>>>(Vp, S);
    k_softmax<<<32768, 256, 0, stream>>>(S);
    k_t1<<<dim3(4, 16, 32), 256, 0, stream>>>(S, Vp, t1);
    k_t2<<<dim3(4, 512), 256, 0, stream>>>(t1, Wc, t2);
    k_O<<<dim3(4, 16, 32), 256, 0, stream>>>(S, t2, resv, out);
}

// Round 2
// 475.897 us; speedup vs baseline: 3.0003x; 3.0003x over previous
//
#include <hip/hip_runtime.h>
#include <math.h>

// B=32, M=1024, D=768, H=256.  bf16 MFMA pipeline:
//  g = mean_m V; gW = g@WVw^T                       (fp32, tiny)
//  Vp   = bf16(alpha*(V@WVw^T) + (1-a)*gW + WVb)    [B,M,H] bf16   (MFMA, A cast from fp32)
//  resv = bf16(V@resw^T + resb)                     [B,M,H] bf16   (fused in same GEMM, N=512)
//  S    = bf16(Vp@Vp^T)                             [B,M,M] bf16 logits
//  P    = softmax_rows(S)  (bf16, in-place)
//  t1   = Pt@VpT^T, t2 = t1@WcT^T, O = relu(P@t2T^T + resv)  (all bf16 MFMA, fp32 acc)
// Workspace ~180 MB.

#define PADK 40  // LDS row stride (bf16 units) for 32-wide K tiles; 80B rows spread banks

typedef __attribute__((ext_vector_type(8))) short bf16x8;
typedef __attribute__((ext_vector_type(4))) float f32x4;

__device__ __forceinline__ ushort f2b(float f) {
    unsigned u = __float_as_uint(f);
    return (ushort)((u + 0x7fffu + ((u >> 16) & 1u)) >> 16);
}
__device__ __forceinline__ float b2f(ushort u) {
    return __uint_as_float((unsigned)u << 16);
}
__device__ __forceinline__ uint4 pack8(float4 a, float4 b) {
    uint4 r;
    r.x = f2b(a.x) | ((unsigned)f2b(a.y) << 16);
    r.y = f2b(a.z) | ((unsigned)f2b(a.w) << 16);
    r.z = f2b(b.x) | ((unsigned)f2b(b.y) << 16);
    r.w = f2b(b.z) | ((unsigned)f2b(b.w) << 16);
    return r;
}

// ---- 128x128 MFMA GEMM core: C = A @ Bt^T, A [128 x K] (lda), Bt [128 x K] (ldb).
// 256 threads = 4 waves in 2x2; each wave 64x64 = 4x4 frags of 16x16x32.
template<bool CASTA>
__device__ __forceinline__ void gemm_core(const void* __restrict__ Av, int lda,
                                          const ushort* __restrict__ Bt, int ldb, int K,
                                          ushort* As, ushort* Bs, f32x4 acc[4][4]) {
    const int tid = threadIdx.x;
    const int lane = tid & 63;
    const int r0 = tid >> 2;        // staging row 0..63 (and +64)
    const int c0 = (tid & 3) * 8;   // staging col (bf16) 0/8/16/24
    const int kg = (lane >> 4) * 8; // frag k-group
    const int rr = lane & 15;       // frag row/col within 16
    const int wave = tid >> 6;
    const int wr = (wave >> 1) * 64, wc = (wave & 1) * 64;
    ushort* as0 = As + r0 * PADK + c0;
    ushort* as1 = As + (r0 + 64) * PADK + c0;
    ushort* bs0 = Bs + r0 * PADK + c0;
    ushort* bs1 = Bs + (r0 + 64) * PADK + c0;
    const ushort* bt0 = Bt + (size_t)r0 * ldb + c0;
    const ushort* bt1 = Bt + (size_t)(r0 + 64) * ldb + c0;

    for (int k0 = 0; k0 < K; k0 += 32) {
        uint4 aw0, aw1;
        if constexpr (CASTA) {
            const float* fA = (const float*)Av;
            const float* pa0 = fA + (size_t)r0 * lda + k0 + c0;
            const float* pa1 = fA + (size_t)(r0 + 64) * lda + k0 + c0;
            aw0 = pack8(*(const float4*)pa0, *(const float4*)(pa0 + 4));
            aw1 = pack8(*(const float4*)pa1, *(const float4*)(pa1 + 4));
        } else {
            const ushort* uA = (const ushort*)Av;
            aw0 = *(const uint4*)(uA + (size_t)r0 * lda + k0 + c0);
            aw1 = *(const uint4*)(uA + (size_t)(r0 + 64) * lda + k0 + c0);
        }
        uint4 bw0 = *(const uint4*)(bt0 + k0);
        uint4 bw1 = *(const uint4*)(bt1 + k0);
        __syncthreads();   // previous iteration's LDS reads done
        *(uint4*)as0 = aw0; *(uint4*)as1 = aw1;
        *(uint4*)bs0 = bw0; *(uint4*)bs1 = bw1;
        __syncthreads();
        bf16x8 av[4], bv[4];
        #pragma unroll
        for (int i = 0; i < 4; ++i) {
            av[i] = *(const bf16x8*)(As + (wr + i * 16 + rr) * PADK + kg);
            bv[i] = *(const bf16x8*)(Bs + (wc + i * 16 + rr) * PADK + kg);
        }
        #pragma unroll
        for (int i = 0; i < 4; ++i)
            #pragma unroll
            for (int j = 0; j < 4; ++j)
                acc[i][j] = __builtin_amdgcn_mfma_f32_16x16x32_bf16(av[i], bv[j], acc[i][j], 0, 0, 0);
    }
}

// C/D layout (16x16x32): col = lane&15, row = (lane>>4)*4 + reg.
#define EPI_COORDS \
    const int lane = threadIdx.x & 63; \
    const int wave = threadIdx.x >> 6; \
    const int rb = (wave >> 1) * 64 + (lane >> 4) * 4; \
    const int cb = (wave & 1) * 64 + (lane & 15);

// ---- k_mean: per-(b, m-chunk, d-tile) partial column sums of V
__global__ __launch_bounds__(256) void k_mean(const float* __restrict__ V, float* __restrict__ gpart) {
    const int b = blockIdx.z, mc = blockIdx.y;
    const int d = blockIdx.x * 256 + threadIdx.x;   // 0..767
    const float* Vb = V + ((size_t)(b * 1024 + mc * 128)) * 768 + d;
    float s = 0.f;
    for (int m = 0; m < 128; ++m) s += Vb[(size_t)m * 768];
    gpart[(size_t)(mc * 32 + b) * 768 + d] = s;
}

__global__ __launch_bounds__(256) void k_gsum(const float* __restrict__ gpart, float* __restrict__ g) {
    int idx = blockIdx.x * 256 + threadIdx.x;       // < 24576
    float s = 0.f;
    #pragma unroll
    for (int c = 0; c < 8; ++c) s += gpart[(size_t)c * 24576 + idx];
    g[idx] = s * (1.0f / 1024.0f);
}

__global__ __launch_bounds__(256) void k_gW(const float* __restrict__ g,
                                            const float* __restrict__ WVw,
                                            float* __restrict__ gW) {
    int idx = blockIdx.x * 256 + threadIdx.x;       // < 8192
    int b = idx >> 8, h = idx & 255;
    const float* gr = g + b * 768;
    const float* wr = WVw + (size_t)h * 768;
    float s = 0.f;
    for (int d = 0; d < 768; ++d) s += gr[d] * wr[d];
    gW[idx] = s;
}

// ---- cast WVw(256x768) ++ resw(256x768) -> Wcat bf16 [512][768]
__global__ __launch_bounds__(256) void k_castw(const float* __restrict__ WVw,
                                               const float* __restrict__ resw,
                                               ushort* __restrict__ Wcat) {
    int id = blockIdx.x * 256 + threadIdx.x;        // < 49152
    int n = id / 96, c = (id - n * 96) * 8;
    const float* src = (n < 256) ? (WVw + (size_t)n * 768 + c) : (resw + (size_t)(n - 256) * 768 + c);
    *(uint4*)(Wcat + (size_t)n * 768 + c) = pack8(*(const float4*)src, *(const float4*)(src + 4));
}

// ---- WcT[k][h] = bf16(Wc[h][k]), 256x256
__global__ __launch_bounds__(256) void k_wct(const float* __restrict__ Wc, ushort* __restrict__ WcT) {
    __shared__ float t[64][65];
    const int r0 = blockIdx.y * 64, c0 = blockIdx.x * 64;
    const int tid = threadIdx.x;
    #pragma unroll
    for (int i = 0; i < 4; ++i) {
        int r = (tid >> 4) + i * 16, c4 = (tid & 15) * 4;
        float4 v = *(const float4*)&Wc[(size_t)(r0 + r) * 256 + c0 + c4];
        t[r][c4] = v.x; t[r][c4 + 1] = v.y; t[r][c4 + 2] = v.z; t[r][c4 + 3] = v.w;
    }
    __syncthreads();
    #pragma unroll
    for (int i = 0; i < 4; ++i) {
        int oc = (tid >> 4) + i * 16, r4 = (tid & 15) * 4;
        unsigned lo = f2b(t[r4][oc]) | ((unsigned)f2b(t[r4 + 1][oc]) << 16);
        unsigned hi = f2b(t[r4 + 2][oc]) | ((unsigned)f2b(t[r4 + 3][oc]) << 16);
        *(uint2*)&WcT[(size_t)(c0 + oc) * 256 + r0 + r4] = make_uint2(lo, hi);
    }
}

// ---- generic per-batch bf16 transpose: out[b][c][r] = in[b][r][c], 64x64 tiles
__global__ __launch_bounds__(256) void k_trb(const ushort* __restrict__ in, ushort* __restrict__ out,
                                             int R, int C, int ldin) {
    __shared__ ushort t[64][68];
    const int b = blockIdx.z;
    const ushort* ib = in + (size_t)b * R * ldin;
    ushort* ob = out + (size_t)b * R * C;
    const int c0 = blockIdx.x * 64, r0 = blockIdx.y * 64;
    const int tid = threadIdx.x;
    #pragma unroll
    for (int i = 0; i < 4; ++i) {
        int r = (tid >> 4) + i * 16, c4 = (tid & 15) * 4;
        *(uint2*)&t[r][c4] = *(const uint2*)(ib + (size_t)(r0 + r) * ldin + c0 + c4);
    }
    __syncthreads();
    #pragma unroll
    for (int i = 0; i < 4; ++i) {
        int oc = (tid >> 4) + i * 16, r4 = (tid & 15) * 4;
        unsigned lo = t[r4][oc] | ((unsigned)t[r4 + 1][oc] << 16);
        unsigned hi = t[r4 + 2][oc] | ((unsigned)t[r4 + 3][oc] << 16);
        *(uint2*)(ob + (size_t)(c0 + oc) * R + r0 + r4) = make_uint2(lo, hi);
    }
}

// ---- k_proj: [32768 x 512] = bf16(V) @ Wcat^T, split epilogue (Vp | resv), both bf16
__global__ __launch_bounds__(256) void k_proj(const float* __restrict__ V, const ushort* __restrict__ Wcat,
                                              const float* __restrict__ WVb, const float* __restrict__ resb,
                                              const float* __restrict__ gW, const float* __restrict__ alpha_p,
                                              ushort* __restrict__ Vp, ushort* __restrict__ resv) {
    __shared__ ushort As[128 * PADK], Bs[128 * PADK];
    f32x4 acc[4][4] = {};
    const int n0 = blockIdx.x * 128, m0 = blockIdx.y * 128;
    gemm_core<true>(V + (size_t)m0 * 768, 768, Wcat + (size_t)n0 * 768, 768, 768, As, Bs, acc);
    EPI_COORDS
    const float alpha = *alpha_p, oma = 1.0f - alpha;
    #pragma unroll
    for (int i = 0; i < 4; ++i)
        #pragma unroll
        for (int j = 0; j < 4; ++j) {
            int gcol = n0 + cb + j * 16;
            #pragma unroll
            for (int r = 0; r < 4; ++r) {
                int grow = m0 + rb + i * 16 + r;
                float v = acc[i][j][r];
                if (gcol < 256) {
                    float o = alpha * v + oma * gW[((grow >> 10) << 8) + gcol] + WVb[gcol];
                    Vp[(size_t)grow * 256 + gcol] = f2b(o);
                } else {
                    resv[(size_t)grow * 256 + gcol - 256] = f2b(v + resb[gcol - 256]);
                }
            }
        }
}

// ---- k_sim: S_b = bf16(Vp_b @ Vp_b^T)
__global__ __launch_bounds__(256) void k_sim(const ushort* __restrict__ Vp, ushort* __restrict__ S) {
    __shared__ ushort As[128 * PADK], Bs[128 * PADK];
    f32x4 acc[4][4] = {};
    const int b = blockIdx.z;
    const ushort* Vb = Vp + (size_t)b * 1024 * 256;
    const int n0 = blockIdx.x * 128, m0 = blockIdx.y * 128;
    gemm_core<false>(Vb + (size_t)m0 * 256, 256, Vb + (size_t)n0 * 256, 256, 256, As, Bs, acc);
    ushort* Sb = S + ((size_t)b << 20);
    EPI_COORDS
    #pragma unroll
    for (int i = 0; i < 4; ++i)
        #pragma unroll
        for (int j = 0; j < 4; ++j)
            #pragma unroll
            for (int r = 0; r < 4; ++r)
                Sb[(size_t)(m0 + rb + i * 16 + r) * 1024 + n0 + cb + j * 16] = f2b(acc[i][j][r]);
}

// ---- k_softmax: bf16 row softmax in place (1024 cols)
__global__ __launch_bounds__(256) void k_softmax(ushort* __restrict__ S) {
    ushort* p = S + (size_t)blockIdx.x * 1024;
    const int tid = threadIdx.x;
    uint2 raw = *(const uint2*)(p + tid * 4);
    float f0 = b2f((ushort)(raw.x & 0xffff));
    float f1 = b2f((ushort)(raw.x >> 16));
    float f2 = b2f((ushort)(raw.y & 0xffff));
    float f3 = b2f((ushort)(raw.y >> 16));
    float lm = fmaxf(fmaxf(f0, f1), fmaxf(f2, f3));
    #pragma unroll
    for (int o = 32; o > 0; o >>= 1) lm = fmaxf(lm, __shfl_xor(lm, o, 64));
    __shared__ float red[4];
    const int wid = tid >> 6, lane = tid & 63;
    if (lane == 0) red[wid] = lm;
    __syncthreads();
    const float m = fmaxf(fmaxf(red[0], red[1]), fmaxf(red[2], red[3]));
    __syncthreads();
    f0 = __expf(f0 - m); f1 = __expf(f1 - m); f2 = __expf(f2 - m); f3 = __expf(f3 - m);
    float ls = f0 + f1 + f2 + f3;
    #pragma unroll
    for (int o = 32; o > 0; o >>= 1) ls += __shfl_xor(ls, o, 64);
    if (lane == 0) red[wid] = ls;
    __syncthreads();
    const float inv = 1.0f / (red[0] + red[1] + red[2] + red[3]);
    unsigned lo = f2b(f0 * inv) | ((unsigned)f2b(f1 * inv) << 16);
    unsigned hi = f2b(f2 * inv) | ((unsigned)f2b(f3 * inv) << 16);
    *(uint2*)(p + tid * 4) = make_uint2(lo, hi);
}

// ---- k_t1: t1_b = Pt_b @ VpT_b^T   [1024x256], K=1024
__global__ __launch_bounds__(256) void k_t1(const ushort* __restrict__ Pt, const ushort* __restrict__ VpT,
                                            ushort* __restrict__ t1) {
    __shared__ ushort As[128 * PADK], Bs[128 * PADK];
    f32x4 acc[4][4] = {};
    const int b = blockIdx.z;
    const int n0 = blockIdx.x * 128, m0 = blockIdx.y * 128;
    gemm_core<false>(Pt + ((size_t)b << 20) + (size_t)m0 * 1024, 1024,
                     VpT + (size_t)b * 256 * 1024 + (size_t)n0 * 1024, 1024, 1024, As, Bs, acc);
    ushort* ob = t1 + (size_t)b * 1024 * 256;
    EPI_COORDS
    #pragma unroll
    for (int i = 0; i < 4; ++i)
        #pragma unroll
        for (int j = 0; j < 4; ++j)
            #pragma unroll
            for (int r = 0; r < 4; ++r)
                ob[(size_t)(m0 + rb + i * 16 + r) * 256 + n0 + cb + j * 16] = f2b(acc[i][j][r]);
}

// ---- k_t2: t2 = t1 @ WcT^T   [32768x256], K=256
__global__ __launch_bounds__(256) void k_t2(const ushort* __restrict__ t1, const ushort* __restrict__ WcT,
                                            ushort* __restrict__ t2) {
    __shared__ ushort As[128 * PADK], Bs[128 * PADK];
    f32x4 acc[4][4] = {};
    const int n0 = blockIdx.x * 128, m0 = blockIdx.y * 128;
    gemm_core<false>(t1 + (size_t)m0 * 256, 256, WcT + (size_t)n0 * 256, 256, 256, As, Bs, acc);
    EPI_COORDS
    #pragma unroll
    for (int i = 0; i < 4; ++i)
        #pragma unroll
        for (int j = 0; j < 4; ++j)
            #pragma unroll
            for (int r = 0; r < 4; ++r)
                t2[(size_t)(m0 + rb + i * 16 + r) * 256 + n0 + cb + j * 16] = f2b(acc[i][j][r]);
}

// ---- k_O: out = relu(P_b @ t2T_b^T + resv), fp32 out
__global__ __launch_bounds__(256) void k_O(const ushort* __restrict__ P, const ushort* __restrict__ t2T,
                                           const ushort* __restrict__ resv, float* __restrict__ out) {
    __shared__ ushort As[128 * PADK], Bs[128 * PADK];
    f32x4 acc[4][4] = {};
    const int b = blockIdx.z;
    const int n0 = blockIdx.x * 128, m0 = blockIdx.y * 128;
    gemm_core<false>(P + ((size_t)b << 20) + (size_t)m0 * 1024, 1024,
                     t2T + (size_t)b * 256 * 1024 + (size_t)n0 * 1024, 1024, 1024, As, Bs, acc);
    EPI_COORDS
    #pragma unroll
    for (int i = 0; i < 4; ++i)
        #pragma unroll
        for (int j = 0; j < 4; ++j)
            #pragma unroll
            for (int r = 0; r < 4; ++r) {
                size_t off = ((size_t)(b * 1024 + m0 + rb + i * 16 + r)) * 256 + n0 + cb + j * 16;
                out[off] = fmaxf(acc[i][j][r] + b2f(resv[off]), 0.0f);
            }
}

extern "C" void kernel_launch(void* const* d_in, const int* in_sizes, int n_in,
                              void* d_out, int out_size, void* d_ws, size_t ws_size,
                              hipStream_t stream) {
    const float* V     = (const float*)d_in[0];
    const float* alpha = (const float*)d_in[1];
    const float* WVw   = (const float*)d_in[2];
    const float* WVb   = (const float*)d_in[3];
    const float* Wc    = (const float*)d_in[4];
    const float* resw  = (const float*)d_in[5];
    const float* resb  = (const float*)d_in[6];
    float* out = (float*)d_out;

    // workspace layout (bytes), ~180 MB total
    char* W = (char*)d_ws;
    ushort* S    = (ushort*)(W);                               // 64 MB: bf16 logits, then P in place
    ushort* Vp   = (ushort*)(W + (64ull << 20));               // 16 MB (dead after trb -> part of Pt)
    ushort* Pt   = (ushort*)(W + (64ull << 20));               // 64 MB spans [64,128) MB
    ushort* VpT  = (ushort*)(W + (128ull << 20));              // 16 MB (t2 aliases after t1)
    ushort* resv = (ushort*)(W + (144ull << 20));              // 16 MB
    ushort* t1   = (ushort*)(W + (160ull << 20));              // 16 MB (t2T aliases after t2)
    ushort* WcT  = (ushort*)(W + (176ull << 20));              // 128 KB
    ushort* Wcat = (ushort*)(W + (177ull << 20));              // 768 KB
    float*  gpart= (float*)(W + (178ull << 20));               // 768 KB
    float*  g    = (float*)(W + (179ull << 20));               // 96 KB
    float*  gW   = (float*)(W + (179ull << 20) + (128u << 10));// 32 KB
    ushort* t2   = VpT;   // alias: VpT dead after k_t1
    ushort* t2T  = t1;    // alias: t1 dead after k_t2

    k_mean<<<dim3(3, 8, 32), 256, 0, stream>>>(V, gpart);
    k_gsum<<<96, 256, 0, stream>>>(gpart, g);
    k_gW<<<32, 256, 0, stream>>>(g, WVw, gW);
    k_castw<<<192, 256, 0, stream>>>(WVw, resw, Wcat);
    k_wct<<<dim3(4, 4), 256, 0, stream>>>(Wc, WcT);
    k_proj<<<dim3(4, 256), 256, 0, stream>>>(V, Wcat, WVb, resb, gW, alpha, Vp, resv);
    k_sim<<<dim3(8, 8, 32), 256, 0, stream>>>(Vp, S);
    k_trb<<<dim3(4, 16, 32), 256, 0, stream>>>(Vp, VpT, 1024, 256, 256);
    k_softmax<<<32768, 256, 0, stream>>>(S);
    k_trb<<<dim3(16, 16, 32), 256, 0, stream>>>(S, Pt, 1024, 1024, 1024);
    k_t1<<<dim3(2, 8, 32), 256, 0, stream>>>(Pt, VpT, t1);
    k_t2<<<dim3(2, 256), 256, 0, stream>>>(t1, WcT, t2);
    k_trb<<<dim3(4, 16, 32), 256, 0, stream>>>(t2, t2T, 1024, 256, 256);
    k_O<<<dim3(2, 8, 32), 256, 0, stream>>>(S, t2T, resv, out);
}

// Round 3
// 469.425 us; speedup vs baseline: 3.0417x; 1.0138x over previous
//
#include <hip/hip_runtime.h>
#include <math.h>

// B=32, M=1024, D=768, H=256.
// Vb = bf16(V); g = mean_m V (fused with cast); gW = g@WVw^T (fp32)
// [Vp | resv] = Vb @ [WVw;resw]^T (+epilogues), bf16      -- MFMA m97-core
// shift[b] = max_m ||Vp_m||^2  (diag of S dominates row max)
// E = exp(Vp@Vp^T - shift[b])  bf16 (symmetric!)          -- MFMA core, exp epilogue
// invZ[m] = 1/sum_n E[m,n]
// t1 = E @ (Vp*invZ)   (= P^T @ Vp, by symmetry)          -- MFMA core
// t2 = t1 @ Wc                                            -- MFMA core
// out = relu(invZ[m]*(E @ t2) + resv)  fp32               -- MFMA core
// No P transpose, no separate softmax pass.

typedef __attribute__((ext_vector_type(8))) short bf16x8;
typedef __attribute__((ext_vector_type(4))) float f32x4;

__device__ __forceinline__ ushort f2b(float f) {
    unsigned u = __float_as_uint(f);
    return (ushort)((u + 0x7fffu + ((u >> 16) & 1u)) >> 16);
}
__device__ __forceinline__ float b2f(ushort u) {
    return __uint_as_float((unsigned)u << 16);
}
__device__ __forceinline__ uint4 pack8(float4 a, float4 b) {
    uint4 r;
    r.x = f2b(a.x) | ((unsigned)f2b(a.y) << 16);
    r.y = f2b(a.z) | ((unsigned)f2b(a.w) << 16);
    r.z = f2b(b.x) | ((unsigned)f2b(b.y) << 16);
    r.w = f2b(b.z) | ((unsigned)f2b(b.w) << 16);
    return r;
}

__device__ __forceinline__ void gl16(const void* g, void* l) {
    __builtin_amdgcn_global_load_lds(
        (__attribute__((address_space(1))) const unsigned*)g,
        (__attribute__((address_space(3))) unsigned*)l, 16, 0, 0);
}

// ---- m97-style 128x128 GEMM core, BK=64, global_load_lds(16B) staging, XOR-swizzled LDS.
// C = A @ Bt^T;  A [128 x K] rows at stride K (bf16), Bt [128 x K] rows at stride K.
// LDS tile layout: LDS[r][c] = G[r][c ^ ((r&7)<<4)] (byte cols), achieved by
// inverse-swizzling the per-lane GLOBAL source (linear LDS dest, rule #21).
__device__ __forceinline__ void gemm_core(const ushort* __restrict__ A,
                                          const ushort* __restrict__ Bt,
                                          int K, ushort* As, ushort* Bs,
                                          f32x4 acc[4][4]) {
    const int tid = threadIdx.x;
    const int lane = tid & 63;
    const int wave = tid >> 6;
    const int l8 = lane >> 3, l7 = lane & 7;
    const int swz = ((l7 ^ l8) << 4);                 // src byte col for this lane
    const char* pa[4];
    const char* pb[4];
    ushort* la[4];
    ushort* lb[4];
    #pragma unroll
    for (int i = 0; i < 4; ++i) {
        int r = (wave * 4 + i) * 8 + l8;              // staged row 0..127
        pa[i] = (const char*)A + (size_t)r * (K * 2) + swz;
        pb[i] = (const char*)Bt + (size_t)r * (K * 2) + swz;
        la[i] = As + (wave * 4 + i) * 512;            // wave-uniform LDS base (1KB/instr)
        lb[i] = Bs + (wave * 4 + i) * 512;
    }
    const int rr = lane & 15;
    const int kq = (lane >> 4) << 4;                  // byte offset of lane's 16B in 64B k-step
    const int mask = (rr & 7) << 4;
    const int c0 = kq ^ mask;                         // ks=0 swizzled byte col
    const int c1 = (64 + kq) ^ mask;                  // ks=1 swizzled byte col
    const int wr = (wave >> 1) * 64, wc = (wave & 1) * 64;
    const int arow0 = (wr + rr) * 128, brow0 = (wc + rr) * 128;

    for (int k0 = 0; k0 < K; k0 += 64) {
        __syncthreads();                              // prev iter's LDS reads done
        #pragma unroll
        for (int i = 0; i < 4; ++i) {
            gl16(pa[i], la[i]);
            gl16(pb[i], lb[i]);
            pa[i] += 128; pb[i] += 128;
        }
        __syncthreads();                              // staging complete (vmcnt drained)
        #pragma unroll
        for (int ks = 0; ks < 2; ++ks) {
            const int cc = ks ? c1 : c0;
            bf16x8 av[4], bv[4];
            #pragma unroll
            for (int i = 0; i < 4; ++i) {
                av[i] = *(const bf16x8*)((const char*)As + arow0 + i * 2048 + cc);
                bv[i] = *(const bf16x8*)((const char*)Bs + brow0 + i * 2048 + cc);
            }
            #pragma unroll
            for (int i = 0; i < 4; ++i)
                #pragma unroll
                for (int j = 0; j < 4; ++j)
                    acc[i][j] = __builtin_amdgcn_mfma_f32_16x16x32_bf16(av[i], bv[j], acc[i][j], 0, 0, 0);
        }
    }
}

// C/D layout (16x16x32): col = lane&15, row = (lane>>4)*4 + reg.
#define EPI_COORDS \
    const int lane = threadIdx.x & 63; \
    const int wave = threadIdx.x >> 6; \
    const int rb = (wave >> 1) * 64 + (lane >> 4) * 4; \
    const int cb = (wave & 1) * 64 + (lane & 15);

// ---- cast V->bf16 fused with column partial sums for the mean
__global__ __launch_bounds__(192) void k_castmean(const float* __restrict__ V,
                                                  ushort* __restrict__ Vb,
                                                  float* __restrict__ gpart) {
    const int b = blockIdx.x, mc = blockIdx.y, t = threadIdx.x;   // t < 192, 4 cols each
    const size_t base = ((size_t)(b * 1024 + mc * 128)) * 768 + t * 4;
    const float* src = V + base;
    ushort* dst = Vb + base;
    float4 s = make_float4(0.f, 0.f, 0.f, 0.f);
    for (int r = 0; r < 128; ++r) {
        float4 v = *(const float4*)(src + (size_t)r * 768);
        s.x += v.x; s.y += v.y; s.z += v.z; s.w += v.w;
        unsigned u0 = f2b(v.x) | ((unsigned)f2b(v.y) << 16);
        unsigned u1 = f2b(v.z) | ((unsigned)f2b(v.w) << 16);
        *(uint2*)(dst + (size_t)r * 768) = make_uint2(u0, u1);
    }
    *(float4*)&gpart[(size_t)(mc * 32 + b) * 768 + t * 4] = s;
}

__global__ __launch_bounds__(256) void k_gsum(const float* __restrict__ gpart, float* __restrict__ g) {
    int idx = blockIdx.x * 256 + threadIdx.x;       // < 24576
    float s = 0.f;
    #pragma unroll
    for (int c = 0; c < 8; ++c) s += gpart[(size_t)c * 24576 + idx];
    g[idx] = s * (1.0f / 1024.0f);
}

__global__ __launch_bounds__(256) void k_gW(const float* __restrict__ g,
                                            const float* __restrict__ WVw,
                                            float* __restrict__ gW) {
    int idx = blockIdx.x * 256 + threadIdx.x;       // < 8192
    int b = idx >> 8, h = idx & 255;
    const float* gr = g + b * 768;
    const float* wr = WVw + (size_t)h * 768;
    float s = 0.f;
    for (int d = 0; d < 768; ++d) s += gr[d] * wr[d];
    gW[idx] = s;
}

// ---- cast WVw(256x768) ++ resw(256x768) -> Wcat bf16 [512][768]
__global__ __launch_bounds__(256) void k_castw(const float* __restrict__ WVw,
                                               const float* __restrict__ resw,
                                               ushort* __restrict__ Wcat) {
    int id = blockIdx.x * 256 + threadIdx.x;        // < 49152
    int n = id / 96, c = (id - n * 96) * 8;
    const float* src = (n < 256) ? (WVw + (size_t)n * 768 + c) : (resw + (size_t)(n - 256) * 768 + c);
    *(uint4*)(Wcat + (size_t)n * 768 + c) = pack8(*(const float4*)src, *(const float4*)(src + 4));
}

// ---- WcT[k][h] = bf16(Wc[h][k]), 256x256
__global__ __launch_bounds__(256) void k_wct(const float* __restrict__ Wc, ushort* __restrict__ WcT) {
    __shared__ float t[64][65];
    const int r0 = blockIdx.y * 64, c0 = blockIdx.x * 64;
    const int tid = threadIdx.x;
    #pragma unroll
    for (int i = 0; i < 4; ++i) {
        int r = (tid >> 4) + i * 16, c4 = (tid & 15) * 4;
        float4 v = *(const float4*)&Wc[(size_t)(r0 + r) * 256 + c0 + c4];
        t[r][c4] = v.x; t[r][c4 + 1] = v.y; t[r][c4 + 2] = v.z; t[r][c4 + 3] = v.w;
    }
    __syncthreads();
    #pragma unroll
    for (int i = 0; i < 4; ++i) {
        int oc = (tid >> 4) + i * 16, r4 = (tid & 15) * 4;
        unsigned lo = f2b(t[r4][oc]) | ((unsigned)f2b(t[r4 + 1][oc]) << 16);
        unsigned hi = f2b(t[r4 + 2][oc]) | ((unsigned)f2b(t[r4 + 3][oc]) << 16);
        *(uint2*)&WcT[(size_t)(c0 + oc) * 256 + r0 + r4] = make_uint2(lo, hi);
    }
}

// ---- k_proj: [32768 x 512] = Vb @ Wcat^T, split epilogue (Vp | resv), both bf16
__global__ __launch_bounds__(256) void k_proj(const ushort* __restrict__ Vb, const ushort* __restrict__ Wcat,
                                              const float* __restrict__ WVb, const float* __restrict__ resb,
                                              const float* __restrict__ gW, const float* __restrict__ alpha_p,
                                              ushort* __restrict__ Vp, ushort* __restrict__ resv) {
    __shared__ ushort As[128 * 64], Bs[128 * 64];
    f32x4 acc[4][4] = {};
    const int n0 = blockIdx.x * 128, m0 = blockIdx.y * 128;
    gemm_core(Vb + (size_t)m0 * 768, Wcat + (size_t)n0 * 768, 768, As, Bs, acc);
    EPI_COORDS
    const float alpha = *alpha_p, oma = 1.0f - alpha;
    #pragma unroll
    for (int i = 0; i < 4; ++i)
        #pragma unroll
        for (int j = 0; j < 4; ++j) {
            int gcol = n0 + cb + j * 16;
            #pragma unroll
            for (int r = 0; r < 4; ++r) {
                int grow = m0 + rb + i * 16 + r;
                float v = acc[i][j][r];
                if (gcol < 256) {
                    float o = alpha * v + oma * gW[((grow >> 10) << 8) + gcol] + WVb[gcol];
                    Vp[(size_t)grow * 256 + gcol] = f2b(o);
                } else {
                    resv[(size_t)grow * 256 + gcol - 256] = f2b(v + resb[gcol - 256]);
                }
            }
        }
}

// ---- k_dmax: shift[b] = max_m ||Vp_m||^2 (fp32 acc from bf16 rows)
__global__ __launch_bounds__(256) void k_dmax(const ushort* __restrict__ Vp, float* __restrict__ shift) {
    const int b = blockIdx.x;
    const int wave = threadIdx.x >> 6, lane = threadIdx.x & 63;
    const ushort* Vb_ = Vp + (size_t)b * 1024 * 256;
    float mx = -1e30f;
    for (int rr = 0; rr < 256; ++rr) {
        int row = wave * 256 + rr;
        uint2 v = *(const uint2*)(Vb_ + (size_t)row * 256 + lane * 4);
        float f0 = b2f((ushort)(v.x & 0xffff)), f1 = b2f((ushort)(v.x >> 16));
        float f2 = b2f((ushort)(v.y & 0xffff)), f3 = b2f((ushort)(v.y >> 16));
        float s = f0 * f0 + f1 * f1 + f2 * f2 + f3 * f3;
        #pragma unroll
        for (int o = 32; o > 0; o >>= 1) s += __shfl_xor(s, o, 64);
        mx = fmaxf(mx, s);
    }
    __shared__ float red[4];
    if (lane == 0) red[wave] = mx;
    __syncthreads();
    if (threadIdx.x == 0)
        shift[b] = fmaxf(fmaxf(red[0], red[1]), fmaxf(red[2], red[3]));
}

// ---- k_sim: E_b = exp(Vp_b @ Vp_b^T - shift[b]), bf16 (symmetric)
__global__ __launch_bounds__(256) void k_sim(const ushort* __restrict__ Vp,
                                             const float* __restrict__ shift,
                                             ushort* __restrict__ E) {
    __shared__ ushort As[128 * 64], Bs[128 * 64];
    f32x4 acc[4][4] = {};
    const int b = blockIdx.z;
    const ushort* Vb_ = Vp + (size_t)b * 1024 * 256;
    const int n0 = blockIdx.x * 128, m0 = blockIdx.y * 128;
    gemm_core(Vb_ + (size_t)m0 * 256, Vb_ + (size_t)n0 * 256, 256, As, Bs, acc);
    ushort* Eb = E + ((size_t)b << 20);
    const float sh = shift[b];
    EPI_COORDS
    #pragma unroll
    for (int i = 0; i < 4; ++i)
        #pragma unroll
        for (int j = 0; j < 4; ++j)
            #pragma unroll
            for (int r = 0; r < 4; ++r)
                Eb[(size_t)(m0 + rb + i * 16 + r) * 1024 + n0 + cb + j * 16] =
                    f2b(__expf(acc[i][j][r] - sh));
}

// ---- k_rowsum: invZ[row] = 1/sum_n E[row][n].  One wave per row.
__global__ __launch_bounds__(256) void k_rowsum(const ushort* __restrict__ E, float* __restrict__ invZ) {
    const int row = blockIdx.x * 4 + (threadIdx.x >> 6);
    const int lane = threadIdx.x & 63;
    const ushort* p = E + (size_t)row * 1024 + lane * 4;
    float s = 0.f;
    #pragma unroll
    for (int pass = 0; pass < 4; ++pass) {
        uint2 v = *(const uint2*)(p + pass * 256);
        s += b2f((ushort)(v.x & 0xffff)) + b2f((ushort)(v.x >> 16))
           + b2f((ushort)(v.y & 0xffff)) + b2f((ushort)(v.y >> 16));
    }
    #pragma unroll
    for (int o = 32; o > 0; o >>= 1) s += __shfl_xor(s, o, 64);
    if (lane == 0) invZ[row] = 1.0f / s;
}

// ---- k_trbs: VpZT[b][h][n] = Vp[b][n][h] * invZ[b*1024+n]  (64x64 transpose tiles)
__global__ __launch_bounds__(256) void k_trbs(const ushort* __restrict__ Vp,
                                              const float* __restrict__ invZ,
                                              ushort* __restrict__ VpZT) {
    __shared__ ushort t[64][68];
    const int b = blockIdx.z;
    const ushort* ib = Vp + (size_t)b * 1024 * 256;
    ushort* ob = VpZT + (size_t)b * 256 * 1024;
    const int c0 = blockIdx.x * 64, r0 = blockIdx.y * 64;
    const int tid = threadIdx.x;
    #pragma unroll
    for (int i = 0; i < 4; ++i) {
        int r = (tid >> 4) + i * 16, c4 = (tid & 15) * 4;
        uint2 v = *(const uint2*)(ib + (size_t)(r0 + r) * 256 + c0 + c4);
        float iz = invZ[b * 1024 + r0 + r];
        unsigned lo = f2b(b2f((ushort)(v.x & 0xffff)) * iz) |
                      ((unsigned)f2b(b2f((ushort)(v.x >> 16)) * iz) << 16);
        unsigned hi = f2b(b2f((ushort)(v.y & 0xffff)) * iz) |
                      ((unsigned)f2b(b2f((ushort)(v.y >> 16)) * iz) << 16);
        *(uint2*)&t[r][c4] = make_uint2(lo, hi);
    }
    __syncthreads();
    #pragma unroll
    for (int i = 0; i < 4; ++i) {
        int oc = (tid >> 4) + i * 16, r4 = (tid & 15) * 4;
        unsigned lo = t[r4][oc] | ((unsigned)t[r4 + 1][oc] << 16);
        unsigned hi = t[r4 + 2][oc] | ((unsigned)t[r4 + 3][oc] << 16);
        *(uint2*)(ob + (size_t)(c0 + oc) * 1024 + r0 + r4) = make_uint2(lo, hi);
    }
}

// ---- k_trb: plain bf16 transpose out[b][c][r] = in[b][r][c], in [1024][256] -> out [256][1024]
__global__ __launch_bounds__(256) void k_trb(const ushort* __restrict__ in, ushort* __restrict__ out) {
    __shared__ ushort t[64][68];
    const int b = blockIdx.z;
    const ushort* ib = in + (size_t)b * 1024 * 256;
    ushort* ob = out + (size_t)b * 256 * 1024;
    const int c0 = blockIdx.x * 64, r0 = blockIdx.y * 64;
    const int tid = threadIdx.x;
    #pragma unroll
    for (int i = 0; i < 4; ++i) {
        int r = (tid >> 4) + i * 16, c4 = (tid & 15) * 4;
        *(uint2*)&t[r][c4] = *(const uint2*)(ib + (size_t)(r0 + r) * 256 + c0 + c4);
    }
    __syncthreads();
    #pragma unroll
    for (int i = 0; i < 4; ++i) {
        int oc = (tid >> 4) + i * 16, r4 = (tid & 15) * 4;
        unsigned lo = t[r4][oc] | ((unsigned)t[r4 + 1][oc] << 16);
        unsigned hi = t[r4 + 2][oc] | ((unsigned)t[r4 + 3][oc] << 16);
        *(uint2*)(ob + (size_t)(c0 + oc) * 1024 + r0 + r4) = make_uint2(lo, hi);
    }
}

// ---- k_t1: t1_b = E_b @ VpZT_b^T   [1024x256], K=1024
__global__ __launch_bounds__(256) void k_t1(const ushort* __restrict__ E, const ushort* __restrict__ VpZT,
                                            ushort* __restrict__ t1) {
    __shared__ ushort As[128 * 64], Bs[128 * 64];
    f32x4 acc[4][4] = {};
    const int b = blockIdx.z;
    const int n0 = blockIdx.x * 128, m0 = blockIdx.y * 128;
    gemm_core(E + ((size_t)b << 20) + (size_t)m0 * 1024,
              VpZT + (size_t)b * 256 * 1024 + (size_t)n0 * 1024, 1024, As, Bs, acc);
    ushort* ob = t1 + (size_t)b * 1024 * 256;
    EPI_COORDS
    #pragma unroll
    for (int i = 0; i < 4; ++i)
        #pragma unroll
        for (int j = 0; j < 4; ++j)
            #pragma unroll
            for (int r = 0; r < 4; ++r)
                ob[(size_t)(m0 + rb + i * 16 + r) * 256 + n0 + cb + j * 16] = f2b(acc[i][j][r]);
}

// ---- k_t2: t2 = t1 @ WcT^T   [32768x256], K=256
__global__ __launch_bounds__(256) void k_t2(const ushort* __restrict__ t1, const ushort* __restrict__ WcT,
                                            ushort* __restrict__ t2) {
    __shared__ ushort As[128 * 64], Bs[128 * 64];
    f32x4 acc[4][4] = {};
    const int n0 = blockIdx.x * 128, m0 = blockIdx.y * 128;
    gemm_core(t1 + (size_t)m0 * 256, WcT + (size_t)n0 * 256, 256, As, Bs, acc);
    EPI_COORDS
    #pragma unroll
    for (int i = 0; i < 4; ++i)
        #pragma unroll
        for (int j = 0; j < 4; ++j)
            #pragma unroll
            for (int r = 0; r < 4; ++r)
                t2[(size_t)(m0 + rb + i * 16 + r) * 256 + n0 + cb + j * 16] = f2b(acc[i][j][r]);
}

// ---- k_O: out = relu(invZ[m] * (E_b @ t2T_b^T) + resv), fp32 out
__global__ __launch_bounds__(256) void k_O(const ushort* __restrict__ E, const ushort* __restrict__ t2T,
                                           const ushort* __restrict__ resv, const float* __restrict__ invZ,
                                           float* __restrict__ out) {
    __shared__ ushort As[128 * 64], Bs[128 * 64];
    f32x4 acc[4][4] = {};
    const int b = blockIdx.z;
    const int n0 = blockIdx.x * 128, m0 = blockIdx.y * 128;
    gemm_core(E + ((size_t)b << 20) + (size_t)m0 * 1024,
              t2T + (size_t)b * 256 * 1024 + (size_t)n0 * 1024, 1024, As, Bs, acc);
    EPI_COORDS
    #pragma unroll
    for (int i = 0; i < 4; ++i)
        #pragma unroll
        for (int j = 0; j < 4; ++j)
            #pragma unroll
            for (int r = 0; r < 4; ++r) {
                int row = m0 + rb + i * 16 + r;
                float iz = invZ[b * 1024 + row];
                size_t off = ((size_t)(b * 1024 + row)) * 256 + n0 + cb + j * 16;
                out[off] = fmaxf(acc[i][j][r] * iz + b2f(resv[off]), 0.0f);
            }
}

extern "C" void kernel_launch(void* const* d_in, const int* in_sizes, int n_in,
                              void* d_out, int out_size, void* d_ws, size_t ws_size,
                              hipStream_t stream) {
    const float* V     = (const float*)d_in[0];
    const float* alpha = (const float*)d_in[1];
    const float* WVw   = (const float*)d_in[2];
    const float* WVb   = (const float*)d_in[3];
    const float* Wc    = (const float*)d_in[4];
    const float* resw  = (const float*)d_in[5];
    const float* resb  = (const float*)d_in[6];
    float* out = (float*)d_out;

    // workspace layout, ~213 MB
    char* W = (char*)d_ws;
    ushort* Vb   = (ushort*)(W);                         // 48 MB
    ushort* E    = (ushort*)(W + (48ull  << 20));        // 64 MB
    ushort* Vp   = (ushort*)(W + (112ull << 20));        // 16 MB
    ushort* resv = (ushort*)(W + (128ull << 20));        // 16 MB
    ushort* VpZT = (ushort*)(W + (144ull << 20));        // 16 MB
    ushort* t1   = (ushort*)(W + (160ull << 20));        // 16 MB
    ushort* t2   = (ushort*)(W + (176ull << 20));        // 16 MB
    ushort* t2T  = (ushort*)(W + (192ull << 20));        // 16 MB
    ushort* Wcat = (ushort*)(W + (208ull << 20));        // 768 KB
    ushort* WcT  = (ushort*)(W + (209ull << 20));        // 128 KB
    float*  gpart= (float*) (W + (210ull << 20));        // 768 KB
    float*  g    = (float*) (W + (211ull << 20));        // 96 KB
    float*  gW   = (float*) (W + (211ull << 20) + (128u << 10)); // 32 KB
    float*  shv  = (float*) (W + (211ull << 20) + (256u << 10)); // 128 B
    float*  invZ = (float*) (W + (212ull << 20));        // 128 KB

    k_castmean<<<dim3(32, 8), 192, 0, stream>>>(V, Vb, gpart);
    k_gsum<<<96, 256, 0, stream>>>(gpart, g);
    k_gW<<<32, 256, 0, stream>>>(g, WVw, gW);
    k_castw<<<192, 256, 0, stream>>>(WVw, resw, Wcat);
    k_wct<<<dim3(4, 4), 256, 0, stream>>>(Wc, WcT);
    k_proj<<<dim3(4, 256), 256, 0, stream>>>(Vb, Wcat, WVb, resb, gW, alpha, Vp, resv);
    k_dmax<<<32, 256, 0, stream>>>(Vp, shv);
    k_sim<<<dim3(8, 8, 32), 256, 0, stream>>>(Vp, shv, E);
    k_rowsum<<<8192, 256, 0, stream>>>(E, invZ);
    k_trbs<<<dim3(4, 16, 32), 256, 0, stream>>>(Vp, invZ, VpZT);
    k_t1<<<dim3(2, 8, 32), 256, 0, stream>>>(E, VpZT, t1);
    k_t2<<<dim3(2, 256), 256, 0, stream>>>(t1, WcT, t2);
    k_trb<<<dim3(4, 16, 32), 256, 0, stream>>>(t2, t2T);
    k_O<<<dim3(2, 8, 32), 256, 0, stream>>>(E, t2T, resv, invZ, out);
}

// Round 5
// 416.769 us; speedup vs baseline: 3.4260x; 1.1263x over previous
//
#include <hip/hip_runtime.h>
#include <math.h>

// B=32, M=1024, D=768, H=256.
// Vb = bf16(V); g = mean_m V (fused with cast); gW = g@WVw^T (fp32)
// [Vp | resv] = Vb @ [WVw;resw]^T (+epilogues), bf16      -- MFMA m97-core
// rn[m] = ||Vp_m||^2 ; shift[b] = max_m rn                (parallel, 2 small kernels)
// E = exp(Vp@Vp^T - shift[b])  bf16 (symmetric), Z[m] += row-sums (fused atomics)
// t1 = E @ (Vp/Z)   (= P^T @ Vp, by symmetry)             -- MFMA core
// t2 = t1 @ Wc                                            -- MFMA core
// out = relu((E @ t2)/Z[m] + resv)  fp32                  -- MFMA core

typedef __attribute__((ext_vector_type(8))) short bf16x8;
typedef __attribute__((ext_vector_type(4))) float f32x4;

__device__ __forceinline__ ushort f2b(float f) {
    unsigned u = __float_as_uint(f);
    return (ushort)((u + 0x7fffu + ((u >> 16) & 1u)) >> 16);
}
__device__ __forceinline__ float b2f(ushort u) {
    return __uint_as_float((unsigned)u << 16);
}
__device__ __forceinline__ uint4 pack8(float4 a, float4 b) {
    uint4 r;
    r.x = f2b(a.x) | ((unsigned)f2b(a.y) << 16);
    r.y = f2b(a.z) | ((unsigned)f2b(a.w) << 16);
    r.z = f2b(b.x) | ((unsigned)f2b(b.y) << 16);
    r.w = f2b(b.z) | ((unsigned)f2b(b.w) << 16);
    return r;
}

__device__ __forceinline__ void gl16(const void* g, void* l) {
    __builtin_amdgcn_global_load_lds(
        (__attribute__((address_space(1))) const unsigned*)g,
        (__attribute__((address_space(3))) unsigned*)l, 16, 0, 0);
}

// ---- m97-style 128x128 GEMM core, BK=64, global_load_lds(16B) staging, XOR-swizzled LDS.
__device__ __forceinline__ void gemm_core(const ushort* __restrict__ A,
                                          const ushort* __restrict__ Bt,
                                          int K, ushort* As, ushort* Bs,
                                          f32x4 acc[4][4]) {
    const int tid = threadIdx.x;
    const int lane = tid & 63;
    const int wave = tid >> 6;
    const int l8 = lane >> 3, l7 = lane & 7;
    const int swz = ((l7 ^ l8) << 4);                 // src byte col for this lane
    const char* pa[4];
    const char* pb[4];
    ushort* la[4];
    ushort* lb[4];
    #pragma unroll
    for (int i = 0; i < 4; ++i) {
        int r = (wave * 4 + i) * 8 + l8;              // staged row 0..127
        pa[i] = (const char*)A + (size_t)r * (K * 2) + swz;
        pb[i] = (const char*)Bt + (size_t)r * (K * 2) + swz;
        la[i] = As + (wave * 4 + i) * 512;            // wave-uniform LDS base (1KB/instr)
        lb[i] = Bs + (wave * 4 + i) * 512;
    }
    const int rr = lane & 15;
    const int kq = (lane >> 4) << 4;                  // byte offset of lane's 16B in 64B k-step
    const int mask = (rr & 7) << 4;
    const int c0 = kq ^ mask;                         // ks=0 swizzled byte col
    const int c1 = (64 + kq) ^ mask;                  // ks=1 swizzled byte col
    const int wr = (wave >> 1) * 64, wc = (wave & 1) * 64;
    const int arow0 = (wr + rr) * 128, brow0 = (wc + rr) * 128;

    for (int k0 = 0; k0 < K; k0 += 64) {
        __syncthreads();                              // prev iter's LDS reads done
        #pragma unroll
        for (int i = 0; i < 4; ++i) {
            gl16(pa[i], la[i]);
            gl16(pb[i], lb[i]);
            pa[i] += 128; pb[i] += 128;
        }
        __syncthreads();                              // staging complete (vmcnt drained)
        #pragma unroll
        for (int ks = 0; ks < 2; ++ks) {
            const int cc = ks ? c1 : c0;
            bf16x8 av[4], bv[4];
            #pragma unroll
            for (int i = 0; i < 4; ++i) {
                av[i] = *(const bf16x8*)((const char*)As + arow0 + i * 2048 + cc);
                bv[i] = *(const bf16x8*)((const char*)Bs + brow0 + i * 2048 + cc);
            }
            #pragma unroll
            for (int i = 0; i < 4; ++i)
                #pragma unroll
                for (int j = 0; j < 4; ++j)
                    acc[i][j] = __builtin_amdgcn_mfma_f32_16x16x32_bf16(av[i], bv[j], acc[i][j], 0, 0, 0);
        }
    }
}

// C/D layout (16x16x32): col = lane&15, row = (lane>>4)*4 + reg.
#define EPI_COORDS \
    const int lane = threadIdx.x & 63; \
    const int wave = threadIdx.x >> 6; \
    const int rb = (wave >> 1) * 64 + (lane >> 4) * 4; \
    const int cb = (wave & 1) * 64 + (lane & 15);

// ---- cast V->bf16 fused with column partial sums for the mean
__global__ __launch_bounds__(192) void k_castmean(const float* __restrict__ V,
                                                  ushort* __restrict__ Vb,
                                                  float* __restrict__ gpart) {
    const int b = blockIdx.x, mc = blockIdx.y, t = threadIdx.x;   // t < 192, 4 cols each
    const size_t base = ((size_t)(b * 1024 + mc * 128)) * 768 + t * 4;
    const float* src = V + base;
    ushort* dst = Vb + base;
    float4 s = make_float4(0.f, 0.f, 0.f, 0.f);
    for (int r = 0; r < 128; ++r) {
        float4 v = *(const float4*)(src + (size_t)r * 768);
        s.x += v.x; s.y += v.y; s.z += v.z; s.w += v.w;
        unsigned u0 = f2b(v.x) | ((unsigned)f2b(v.y) << 16);
        unsigned u1 = f2b(v.z) | ((unsigned)f2b(v.w) << 16);
        *(uint2*)(dst + (size_t)r * 768) = make_uint2(u0, u1);
    }
    *(float4*)&gpart[(size_t)(mc * 32 + b) * 768 + t * 4] = s;
}

__global__ __launch_bounds__(256) void k_gsum(const float* __restrict__ gpart, float* __restrict__ g) {
    int idx = blockIdx.x * 256 + threadIdx.x;       // < 24576
    float s = 0.f;
    #pragma unroll
    for (int c = 0; c < 8; ++c) s += gpart[(size_t)c * 24576 + idx];
    g[idx] = s * (1.0f / 1024.0f);
}

__global__ __launch_bounds__(256) void k_gW(const float* __restrict__ g,
                                            const float* __restrict__ WVw,
                                            float* __restrict__ gW) {
    int idx = blockIdx.x * 256 + threadIdx.x;       // < 8192
    int b = idx >> 8, h = idx & 255;
    const float* gr = g + b * 768;
    const float* wr = WVw + (size_t)h * 768;
    float s = 0.f;
    for (int d = 0; d < 768; ++d) s += gr[d] * wr[d];
    gW[idx] = s;
}

// ---- cast WVw(256x768) ++ resw(256x768) -> Wcat bf16 [512][768]
__global__ __launch_bounds__(256) void k_castw(const float* __restrict__ WVw,
                                               const float* __restrict__ resw,
                                               ushort* __restrict__ Wcat) {
    int id = blockIdx.x * 256 + threadIdx.x;        // < 49152
    int n = id / 96, c = (id - n * 96) * 8;
    const float* src = (n < 256) ? (WVw + (size_t)n * 768 + c) : (resw + (size_t)(n - 256) * 768 + c);
    *(uint4*)(Wcat + (size_t)n * 768 + c) = pack8(*(const float4*)src, *(const float4*)(src + 4));
}

// ---- WcT[k][h] = bf16(Wc[h][k]), 256x256
__global__ __launch_bounds__(256) void k_wct(const float* __restrict__ Wc, ushort* __restrict__ WcT) {
    __shared__ float t[64][65];
    const int r0 = blockIdx.y * 64, c0 = blockIdx.x * 64;
    const int tid = threadIdx.x;
    #pragma unroll
    for (int i = 0; i < 4; ++i) {
        int r = (tid >> 4) + i * 16, c4 = (tid & 15) * 4;
        float4 v = *(const float4*)&Wc[(size_t)(r0 + r) * 256 + c0 + c4];
        t[r][c4] = v.x; t[r][c4 + 1] = v.y; t[r][c4 + 2] = v.z; t[r][c4 + 3] = v.w;
    }
    __syncthreads();
    #pragma unroll
    for (int i = 0; i < 4; ++i) {
        int oc = (tid >> 4) + i * 16, r4 = (tid & 15) * 4;
        unsigned lo = f2b(t[r4][oc]) | ((unsigned)f2b(t[r4 + 1][oc]) << 16);
        unsigned hi = f2b(t[r4 + 2][oc]) | ((unsigned)f2b(t[r4 + 3][oc]) << 16);
        *(uint2*)&WcT[(size_t)(c0 + oc) * 256 + r0 + r4] = make_uint2(lo, hi);
    }
}

// ---- k_proj: [32768 x 512] = Vb @ Wcat^T, split epilogue (Vp | resv), both bf16
__global__ __launch_bounds__(256) void k_proj(const ushort* __restrict__ Vb, const ushort* __restrict__ Wcat,
                                              const float* __restrict__ WVb, const float* __restrict__ resb,
                                              const float* __restrict__ gW, const float* __restrict__ alpha_p,
                                              ushort* __restrict__ Vp, ushort* __restrict__ resv) {
    __shared__ ushort As[128 * 64], Bs[128 * 64];
    f32x4 acc[4][4] = {};
    const int n0 = blockIdx.x * 128, m0 = blockIdx.y * 128;
    gemm_core(Vb + (size_t)m0 * 768, Wcat + (size_t)n0 * 768, 768, As, Bs, acc);
    EPI_COORDS
    const float alpha = *alpha_p, oma = 1.0f - alpha;
    #pragma unroll
    for (int i = 0; i < 4; ++i)
        #pragma unroll
        for (int j = 0; j < 4; ++j) {
            int gcol = n0 + cb + j * 16;
            #pragma unroll
            for (int r = 0; r < 4; ++r) {
                int grow = m0 + rb + i * 16 + r;
                float v = acc[i][j][r];
                if (gcol < 256) {
                    float o = alpha * v + oma * gW[((grow >> 10) << 8) + gcol] + WVb[gcol];
                    Vp[(size_t)grow * 256 + gcol] = f2b(o);
                } else {
                    resv[(size_t)grow * 256 + gcol - 256] = f2b(v + resb[gcol - 256]);
                }
            }
        }
}

// ---- k_rownorm: rn[row] = ||Vp_row||^2.  One wave per row, 8192 blocks.
__global__ __launch_bounds__(256) void k_rownorm(const ushort* __restrict__ Vp, float* __restrict__ rn) {
    const int row = blockIdx.x * 4 + (threadIdx.x >> 6);
    const int lane = threadIdx.x & 63;
    uint2 v = *(const uint2*)(Vp + (size_t)row * 256 + lane * 4);
    float f0 = b2f((ushort)(v.x & 0xffff)), f1 = b2f((ushort)(v.x >> 16));
    float f2 = b2f((ushort)(v.y & 0xffff)), f3 = b2f((ushort)(v.y >> 16));
    float s = f0 * f0 + f1 * f1 + f2 * f2 + f3 * f3;
    #pragma unroll
    for (int o = 32; o > 0; o >>= 1) s += __shfl_xor(s, o, 64);
    if (lane == 0) rn[row] = s;
}

// ---- k_shift: shift[b] = max over 1024 rn values
__global__ __launch_bounds__(256) void k_shift(const float* __restrict__ rn, float* __restrict__ shift) {
    const int b = blockIdx.x, tid = threadIdx.x;
    const float* p = rn + b * 1024;
    float m = fmaxf(fmaxf(p[tid], p[tid + 256]), fmaxf(p[tid + 512], p[tid + 768]));
    #pragma unroll
    for (int o = 32; o > 0; o >>= 1) m = fmaxf(m, __shfl_xor(m, o, 64));
    __shared__ float red[4];
    if ((tid & 63) == 0) red[tid >> 6] = m;
    __syncthreads();
    if (tid == 0)
        shift[b] = fmaxf(fmaxf(red[0], red[1]), fmaxf(red[2], red[3]));
}

// ---- k_sim: E_b = exp(Vp_b @ Vp_b^T - shift[b]) bf16, with fused row-sum atomics into Z
__global__ __launch_bounds__(256) void k_sim(const ushort* __restrict__ Vp,
                                             const float* __restrict__ shift,
                                             ushort* __restrict__ E,
                                             float* __restrict__ Z) {
    __shared__ ushort As[128 * 64], Bs[128 * 64];
    f32x4 acc[4][4] = {};
    const int b = blockIdx.z;
    const ushort* Vb_ = Vp + (size_t)b * 1024 * 256;
    const int n0 = blockIdx.x * 128, m0 = blockIdx.y * 128;
    gemm_core(Vb_ + (size_t)m0 * 256, Vb_ + (size_t)n0 * 256, 256, As, Bs, acc);
    ushort* Eb = E + ((size_t)b << 20);
    const float sh = shift[b];
    EPI_COORDS
    #pragma unroll
    for (int i = 0; i < 4; ++i)
        #pragma unroll
        for (int r = 0; r < 4; ++r) {
            const int row = m0 + rb + i * 16 + r;
            float e[4];
            float s = 0.f;
            #pragma unroll
            for (int j = 0; j < 4; ++j) {
                e[j] = __expf(acc[i][j][r] - sh);
                s += e[j];
                Eb[(size_t)row * 1024 + n0 + cb + j * 16] = f2b(e[j]);
            }
            // sum across the 16 lanes sharing this row (lane&15 varies)
            s += __shfl_xor(s, 1, 64);
            s += __shfl_xor(s, 2, 64);
            s += __shfl_xor(s, 4, 64);
            s += __shfl_xor(s, 8, 64);
            if ((lane & 15) == 0)
                atomicAdd(&Z[b * 1024 + row], s);
        }
}

// ---- k_trbs: VpZT[b][h][n] = Vp[b][n][h] / Z[b*1024+n]  (64x64 transpose tiles)
__global__ __launch_bounds__(256) void k_trbs(const ushort* __restrict__ Vp,
                                              const float* __restrict__ Z,
                                              ushort* __restrict__ VpZT) {
    __shared__ ushort t[64][68];
    const int b = blockIdx.z;
    const ushort* ib = Vp + (size_t)b * 1024 * 256;
    ushort* ob = VpZT + (size_t)b * 256 * 1024;
    const int c0 = blockIdx.x * 64, r0 = blockIdx.y * 64;
    const int tid = threadIdx.x;
    #pragma unroll
    for (int i = 0; i < 4; ++i) {
        int r = (tid >> 4) + i * 16, c4 = (tid & 15) * 4;
        uint2 v = *(const uint2*)(ib + (size_t)(r0 + r) * 256 + c0 + c4);
        float iz = 1.0f / Z[b * 1024 + r0 + r];
        unsigned lo = f2b(b2f((ushort)(v.x & 0xffff)) * iz) |
                      ((unsigned)f2b(b2f((ushort)(v.x >> 16)) * iz) << 16);
        unsigned hi = f2b(b2f((ushort)(v.y & 0xffff)) * iz) |
                      ((unsigned)f2b(b2f((ushort)(v.y >> 16)) * iz) << 16);
        *(uint2*)&t[r][c4] = make_uint2(lo, hi);
    }
    __syncthreads();
    #pragma unroll
    for (int i = 0; i < 4; ++i) {
        int oc = (tid >> 4) + i * 16, r4 = (tid & 15) * 4;
        unsigned lo = t[r4][oc] | ((unsigned)t[r4 + 1][oc] << 16);
        unsigned hi = t[r4 + 2][oc] | ((unsigned)t[r4 + 3][oc] << 16);
        *(uint2*)(ob + (size_t)(c0 + oc) * 1024 + r0 + r4) = make_uint2(lo, hi);
    }
}

// ---- k_trb: plain bf16 transpose, in [1024][256] -> out [256][1024]
__global__ __launch_bounds__(256) void k_trb(const ushort* __restrict__ in, ushort* __restrict__ out) {
    __shared__ ushort t[64][68];
    const int b = blockIdx.z;
    const ushort* ib = in + (size_t)b * 1024 * 256;
    ushort* ob = out + (size_t)b * 256 * 1024;
    const int c0 = blockIdx.x * 64, r0 = blockIdx.y * 64;
    const int tid = threadIdx.x;
    #pragma unroll
    for (int i = 0; i < 4; ++i) {
        int r = (tid >> 4) + i * 16, c4 = (tid & 15) * 4;
        *(uint2*)&t[r][c4] = *(const uint2*)(ib + (size_t)(r0 + r) * 256 + c0 + c4);
    }
    __syncthreads();
    #pragma unroll
    for (int i = 0; i < 4; ++i) {
        int oc = (tid >> 4) + i * 16, r4 = (tid & 15) * 4;
        unsigned lo = t[r4][oc] | ((unsigned)t[r4 + 1][oc] << 16);
        unsigned hi = t[r4 + 2][oc] | ((unsigned)t[r4 + 3][oc] << 16);
        *(uint2*)(ob + (size_t)(c0 + oc) * 1024 + r0 + r4) = make_uint2(lo, hi);
    }
}

// ---- k_t1: t1_b = E_b @ VpZT_b^T   [1024x256], K=1024
__global__ __launch_bounds__(256) void k_t1(const ushort* __restrict__ E, const ushort* __restrict__ VpZT,
                                            ushort* __restrict__ t1) {
    __shared__ ushort As[128 * 64], Bs[128 * 64];
    f32x4 acc[4][4] = {};
    const int b = blockIdx.z;
    const int n0 = blockIdx.x * 128, m0 = blockIdx.y * 128;
    gemm_core(E + ((size_t)b << 20) + (size_t)m0 * 1024,
              VpZT + (size_t)b * 256 * 1024 + (size_t)n0 * 1024, 1024, As, Bs, acc);
    ushort* ob = t1 + (size_t)b * 1024 * 256;
    EPI_COORDS
    #pragma unroll
    for (int i = 0; i < 4; ++i)
        #pragma unroll
        for (int j = 0; j < 4; ++j)
            #pragma unroll
            for (int r = 0; r < 4; ++r)
                ob[(size_t)(m0 + rb + i * 16 + r) * 256 + n0 + cb + j * 16] = f2b(acc[i][j][r]);
}

// ---- k_t2: t2 = t1 @ WcT^T   [32768x256], K=256
__global__ __launch_bounds__(256) void k_t2(const ushort* __restrict__ t1, const ushort* __restrict__ WcT,
                                            ushort* __restrict__ t2) {
    __shared__ ushort As[128 * 64], Bs[128 * 64];
    f32x4 acc[4][4] = {};
    const int n0 = blockIdx.x * 128, m0 = blockIdx.y * 128;
    gemm_core(t1 + (size_t)m0 * 256, WcT + (size_t)n0 * 256, 256, As, Bs, acc);
    EPI_COORDS
    #pragma unroll
    for (int i = 0; i < 4; ++i)
        #pragma unroll
        for (int j = 0; j < 4; ++j)
            #pragma unroll
            for (int r = 0; r < 4; ++r)
                t2[(size_t)(m0 + rb + i * 16 + r) * 256 + n0 + cb + j * 16] = f2b(acc[i][j][r]);
}

// ---- k_O: out = relu((E_b @ t2T_b^T)/Z[m] + resv), fp32 out
__global__ __launch_bounds__(256) void k_O(const ushort* __restrict__ E, const ushort* __restrict__ t2T,
                                           const ushort* __restrict__ resv, const float* __restrict__ Z,
                                           float* __restrict__ out) {
    __shared__ ushort As[128 * 64], Bs[128 * 64];
    f32x4 acc[4][4] = {};
    const int b = blockIdx.z;
    const int n0 = blockIdx.x * 128, m0 = blockIdx.y * 128;
    gemm_core(E + ((size_t)b << 20) + (size_t)m0 * 1024,
              t2T + (size_t)b * 256 * 1024 + (size_t)n0 * 1024, 1024, As, Bs, acc);
    EPI_COORDS
    #pragma unroll
    for (int i = 0; i < 4; ++i)
        #pragma unroll
        for (int j = 0; j < 4; ++j)
            #pragma unroll
            for (int r = 0; r < 4; ++r) {
                int row = m0 + rb + i * 16 + r;
                float iz = 1.0f / Z[b * 1024 + row];
                size_t off = ((size_t)(b * 1024 + row)) * 256 + n0 + cb + j * 16;
                out[off] = fmaxf(acc[i][j][r] * iz + b2f(resv[off]), 0.0f);
            }
}

extern "C" void kernel_launch(void* const* d_in, const int* in_sizes, int n_in,
                              void* d_out, int out_size, void* d_ws, size_t ws_size,
                              hipStream_t stream) {
    const float* V     = (const float*)d_in[0];
    const float* alpha = (const float*)d_in[1];
    const float* WVw   = (const float*)d_in[2];
    const float* WVb   = (const float*)d_in[3];
    const float* Wc    = (const float*)d_in[4];
    const float* resw  = (const float*)d_in[5];
    const float* resb  = (const float*)d_in[6];
    float* out = (float*)d_out;

    // workspace layout, ~213 MB
    char* W = (char*)d_ws;
    ushort* Vb   = (ushort*)(W);                         // 48 MB
    ushort* E    = (ushort*)(W + (48ull  << 20));        // 64 MB
    ushort* Vp   = (ushort*)(W + (112ull << 20));        // 16 MB
    ushort* resv = (ushort*)(W + (128ull << 20));        // 16 MB
    ushort* VpZT = (ushort*)(W + (144ull << 20));        // 16 MB
    ushort* t1   = (ushort*)(W + (160ull << 20));        // 16 MB
    ushort* t2   = (ushort*)(W + (176ull << 20));        // 16 MB
    ushort* t2T  = (ushort*)(W + (192ull << 20));        // 16 MB
    ushort* Wcat = (ushort*)(W + (208ull << 20));        // 768 KB
    ushort* WcT  = (ushort*)(W + (209ull << 20));        // 128 KB
    float*  gpart= (float*) (W + (210ull << 20));        // 768 KB
    float*  g    = (float*) (W + (211ull << 20));        // 96 KB
    float*  gW   = (float*) (W + (211ull << 20) + (128u << 10)); // 32 KB
    float*  shv  = (float*) (W + (211ull << 20) + (256u << 10)); // 128 B
    float*  rn   = (float*) (W + (211ull << 20) + (512u << 10)); // 128 KB
    float*  Z    = (float*) (W + (212ull << 20));        // 128 KB

    hipMemsetAsync(Z, 0, 32768 * sizeof(float), stream);  // Z accumulated via atomics

    k_castmean<<<dim3(32, 8), 192, 0, stream>>>(V, Vb, gpart);
    k_gsum<<<96, 256, 0, stream>>>(gpart, g);
    k_gW<<<32, 256, 0, stream>>>(g, WVw, gW);
    k_castw<<<192, 256, 0, stream>>>(WVw, resw, Wcat);
    k_wct<<<dim3(4, 4), 256, 0, stream>>>(Wc, WcT);
    k_proj<<<dim3(4, 256), 256, 0, stream>>>(Vb, Wcat, WVb, resb, gW, alpha, Vp, resv);
    k_rownorm<<<8192, 256, 0, stream>>>(Vp, rn);
    k_shift<<<32, 256, 0, stream>>>(rn, shv);
    k_sim<<<dim3(8, 8, 32), 256, 0, stream>>>(Vp, shv, E, Z);
    k_trbs<<<dim3(4, 16, 32), 256, 0, stream>>>(Vp, Z, VpZT);
    k_t1<<<dim3(2, 8, 32), 256, 0, stream>>>(E, VpZT, t1);
    k_t2<<<dim3(2, 256), 256, 0, stream>>>(t1, WcT, t2);
    k_trb<<<dim3(4, 16, 32), 256, 0, stream>>>(t2, t2T);
    k_O<<<dim3(2, 8, 32), 256, 0, stream>>>(E, t2T, resv, Z, out);
}

// Round 6
// 384.807 us; speedup vs baseline: 3.7106x; 1.0831x over previous
//
#include <hip/hip_runtime.h>
#include <math.h>

// B=32, M=1024, D=768, H=256.
// Vb = bf16(V); g = mean_m V (fused with cast); gW = g@WVw^T (fp32)
// [Vp | resv] = Vb @ [WVw;resw]^T (+epilogues), bf16      -- MFMA m97-core, XCD-swizzled
// rn[m] = ||Vp_m||^2 ; shift[b] = max_m rn
// E = exp(Vp@Vp^T - shift[b]) bf16 (symmetric), Z[m] += row-sums (fused atomics)
// k_t12 (fused): t1 = E @ (Vp/Z) -> LDS; t2 = t1 @ Wc; writes t2T directly
// out = relu((E @ t2T^T)/Z[m] + resv)  fp32               -- MFMA core

typedef __attribute__((ext_vector_type(8))) short bf16x8;
typedef __attribute__((ext_vector_type(4))) float f32x4;

__device__ __forceinline__ ushort f2b(float f) {
    unsigned u = __float_as_uint(f);
    return (ushort)((u + 0x7fffu + ((u >> 16) & 1u)) >> 16);
}
__device__ __forceinline__ float b2f(ushort u) {
    return __uint_as_float((unsigned)u << 16);
}
__device__ __forceinline__ uint4 pack8(float4 a, float4 b) {
    uint4 r;
    r.x = f2b(a.x) | ((unsigned)f2b(a.y) << 16);
    r.y = f2b(a.z) | ((unsigned)f2b(a.w) << 16);
    r.z = f2b(b.x) | ((unsigned)f2b(b.y) << 16);
    r.w = f2b(b.z) | ((unsigned)f2b(b.w) << 16);
    return r;
}

__device__ __forceinline__ void gl16(const void* g, void* l) {
    __builtin_amdgcn_global_load_lds(
        (__attribute__((address_space(1))) const unsigned*)g,
        (__attribute__((address_space(3))) unsigned*)l, 16, 0, 0);
}

// ---- m97-style 128x128 GEMM core, BK=64, global_load_lds(16B), XOR-swizzled LDS.
__device__ __forceinline__ void gemm_core(const ushort* __restrict__ A,
                                          const ushort* __restrict__ Bt,
                                          int K, ushort* As, ushort* Bs,
                                          f32x4 acc[4][4]) {
    const int tid = threadIdx.x;
    const int lane = tid & 63;
    const int wave = tid >> 6;
    const int l8 = lane >> 3, l7 = lane & 7;
    const int swz = ((l7 ^ l8) << 4);
    const char* pa[4];
    const char* pb[4];
    ushort* la[4];
    ushort* lb[4];
    #pragma unroll
    for (int i = 0; i < 4; ++i) {
        int r = (wave * 4 + i) * 8 + l8;
        pa[i] = (const char*)A + (size_t)r * (K * 2) + swz;
        pb[i] = (const char*)Bt + (size_t)r * (K * 2) + swz;
        la[i] = As + (wave * 4 + i) * 512;
        lb[i] = Bs + (wave * 4 + i) * 512;
    }
    const int rr = lane & 15;
    const int kq = (lane >> 4) << 4;
    const int mask = (rr & 7) << 4;
    const int c0 = kq ^ mask;
    const int c1 = (64 + kq) ^ mask;
    const int wr = (wave >> 1) * 64, wc = (wave & 1) * 64;
    const int arow0 = (wr + rr) * 128, brow0 = (wc + rr) * 128;

    for (int k0 = 0; k0 < K; k0 += 64) {
        __syncthreads();
        #pragma unroll
        for (int i = 0; i < 4; ++i) {
            gl16(pa[i], la[i]);
            gl16(pb[i], lb[i]);
            pa[i] += 128; pb[i] += 128;
        }
        __syncthreads();
        #pragma unroll
        for (int ks = 0; ks < 2; ++ks) {
            const int cc = ks ? c1 : c0;
            bf16x8 av[4], bv[4];
            #pragma unroll
            for (int i = 0; i < 4; ++i) {
                av[i] = *(const bf16x8*)((const char*)As + arow0 + i * 2048 + cc);
                bv[i] = *(const bf16x8*)((const char*)Bs + brow0 + i * 2048 + cc);
            }
            #pragma unroll
            for (int i = 0; i < 4; ++i)
                #pragma unroll
                for (int j = 0; j < 4; ++j)
                    acc[i][j] = __builtin_amdgcn_mfma_f32_16x16x32_bf16(av[i], bv[j], acc[i][j], 0, 0, 0);
        }
    }
}

#define EPI_COORDS \
    const int lane = threadIdx.x & 63; \
    const int wave = threadIdx.x >> 6; \
    const int rb = (wave >> 1) * 64 + (lane >> 4) * 4; \
    const int cb = (wave & 1) * 64 + (lane & 15);

// ---- cast V->bf16 fused with column partial sums for the mean (16 row-chunks of 64)
__global__ __launch_bounds__(192) void k_castmean(const float* __restrict__ V,
                                                  ushort* __restrict__ Vb,
                                                  float* __restrict__ gpart) {
    const int b = blockIdx.x, mc = blockIdx.y, t = threadIdx.x;
    const size_t base = ((size_t)(b * 1024 + mc * 64)) * 768 + t * 4;
    const float* src = V + base;
    ushort* dst = Vb + base;
    float4 s = make_float4(0.f, 0.f, 0.f, 0.f);
    for (int r = 0; r < 64; ++r) {
        float4 v = *(const float4*)(src + (size_t)r * 768);
        s.x += v.x; s.y += v.y; s.z += v.z; s.w += v.w;
        unsigned u0 = f2b(v.x) | ((unsigned)f2b(v.y) << 16);
        unsigned u1 = f2b(v.z) | ((unsigned)f2b(v.w) << 16);
        *(uint2*)(dst + (size_t)r * 768) = make_uint2(u0, u1);
    }
    *(float4*)&gpart[(size_t)(mc * 32 + b) * 768 + t * 4] = s;
}

__global__ __launch_bounds__(256) void k_gsum(const float* __restrict__ gpart, float* __restrict__ g) {
    int idx = blockIdx.x * 256 + threadIdx.x;       // < 24576
    float s = 0.f;
    #pragma unroll
    for (int c = 0; c < 16; ++c) s += gpart[(size_t)c * 24576 + idx];
    g[idx] = s * (1.0f / 1024.0f);
}

__global__ __launch_bounds__(256) void k_gW(const float* __restrict__ g,
                                            const float* __restrict__ WVw,
                                            float* __restrict__ gW) {
    int idx = blockIdx.x * 256 + threadIdx.x;       // < 8192
    int b = idx >> 8, h = idx & 255;
    const float* gr = g + b * 768;
    const float* wr = WVw + (size_t)h * 768;
    float s = 0.f;
    for (int d = 0; d < 768; ++d) s += gr[d] * wr[d];
    gW[idx] = s;
}

__global__ __launch_bounds__(256) void k_castw(const float* __restrict__ WVw,
                                               const float* __restrict__ resw,
                                               ushort* __restrict__ Wcat) {
    int id = blockIdx.x * 256 + threadIdx.x;        // < 49152
    int n = id / 96, c = (id - n * 96) * 8;
    const float* src = (n < 256) ? (WVw + (size_t)n * 768 + c) : (resw + (size_t)(n - 256) * 768 + c);
    *(uint4*)(Wcat + (size_t)n * 768 + c) = pack8(*(const float4*)src, *(const float4*)(src + 4));
}

// ---- WcT[k][h] = bf16(Wc[h][k]), 256x256
__global__ __launch_bounds__(256) void k_wct(const float* __restrict__ Wc, ushort* __restrict__ WcT) {
    __shared__ float t[64][65];
    const int r0 = blockIdx.y * 64, c0 = blockIdx.x * 64;
    const int tid = threadIdx.x;
    #pragma unroll
    for (int i = 0; i < 4; ++i) {
        int r = (tid >> 4) + i * 16, c4 = (tid & 15) * 4;
        float4 v = *(const float4*)&Wc[(size_t)(r0 + r) * 256 + c0 + c4];
        t[r][c4] = v.x; t[r][c4 + 1] = v.y; t[r][c4 + 2] = v.z; t[r][c4 + 3] = v.w;
    }
    __syncthreads();
    #pragma unroll
    for (int i = 0; i < 4; ++i) {
        int oc = (tid >> 4) + i * 16, r4 = (tid & 15) * 4;
        unsigned lo = f2b(t[r4][oc]) | ((unsigned)f2b(t[r4 + 1][oc]) << 16);
        unsigned hi = f2b(t[r4 + 2][oc]) | ((unsigned)f2b(t[r4 + 3][oc]) << 16);
        *(uint2*)&WcT[(size_t)(c0 + oc) * 256 + r0 + r4] = make_uint2(lo, hi);
    }
}

// ---- k_proj: [32768 x 512] = Vb @ Wcat^T.  1-D grid 1024, XCD-swizzled.
__global__ __launch_bounds__(256) void k_proj(const ushort* __restrict__ Vb, const ushort* __restrict__ Wcat,
                                              const float* __restrict__ WVb, const float* __restrict__ resb,
                                              const float* __restrict__ gW, const float* __restrict__ alpha_p,
                                              ushort* __restrict__ Vp, ushort* __restrict__ resv) {
    __shared__ ushort As[128 * 64], Bs[128 * 64];
    f32x4 acc[4][4] = {};
    const int j = (blockIdx.x & 7) * 128 + (blockIdx.x >> 3);  // bijective, nwg%8==0
    const int n0 = (j & 3) * 128, m0 = (j >> 2) * 128;
    gemm_core(Vb + (size_t)m0 * 768, Wcat + (size_t)n0 * 768, 768, As, Bs, acc);
    EPI_COORDS
    const float alpha = *alpha_p, oma = 1.0f - alpha;
    #pragma unroll
    for (int i = 0; i < 4; ++i)
        #pragma unroll
        for (int jj = 0; jj < 4; ++jj) {
            int gcol = n0 + cb + jj * 16;
            #pragma unroll
            for (int r = 0; r < 4; ++r) {
                int grow = m0 + rb + i * 16 + r;
                float v = acc[i][jj][r];
                if (gcol < 256) {
                    float o = alpha * v + oma * gW[((grow >> 10) << 8) + gcol] + WVb[gcol];
                    Vp[(size_t)grow * 256 + gcol] = f2b(o);
                } else {
                    resv[(size_t)grow * 256 + gcol - 256] = f2b(v + resb[gcol - 256]);
                }
            }
        }
}

// ---- k_rownorm: rn[row] = ||Vp_row||^2
__global__ __launch_bounds__(256) void k_rownorm(const ushort* __restrict__ Vp, float* __restrict__ rn) {
    const int row = blockIdx.x * 4 + (threadIdx.x >> 6);
    const int lane = threadIdx.x & 63;
    uint2 v = *(const uint2*)(Vp + (size_t)row * 256 + lane * 4);
    float f0 = b2f((ushort)(v.x & 0xffff)), f1 = b2f((ushort)(v.x >> 16));
    float f2 = b2f((ushort)(v.y & 0xffff)), f3 = b2f((ushort)(v.y >> 16));
    float s = f0 * f0 + f1 * f1 + f2 * f2 + f3 * f3;
    #pragma unroll
    for (int o = 32; o > 0; o >>= 1) s += __shfl_xor(s, o, 64);
    if (lane == 0) rn[row] = s;
}

__global__ __launch_bounds__(256) void k_shift(const float* __restrict__ rn, float* __restrict__ shift) {
    const int b = blockIdx.x, tid = threadIdx.x;
    const float* p = rn + b * 1024;
    float m = fmaxf(fmaxf(p[tid], p[tid + 256]), fmaxf(p[tid + 512], p[tid + 768]));
    #pragma unroll
    for (int o = 32; o > 0; o >>= 1) m = fmaxf(m, __shfl_xor(m, o, 64));
    __shared__ float red[4];
    if ((tid & 63) == 0) red[tid >> 6] = m;
    __syncthreads();
    if (tid == 0)
        shift[b] = fmaxf(fmaxf(red[0], red[1]), fmaxf(red[2], red[3]));
}

// ---- k_sim: E_b = exp(Vp_b @ Vp_b^T - shift[b]) bf16, fused row-sum atomics into Z.
__global__ __launch_bounds__(256) void k_sim(const ushort* __restrict__ Vp,
                                             const float* __restrict__ shift,
                                             ushort* __restrict__ E,
                                             float* __restrict__ Z) {
    __shared__ ushort As[128 * 64], Bs[128 * 64];
    f32x4 acc[4][4] = {};
    const int j = (blockIdx.x & 7) * 256 + (blockIdx.x >> 3);
    const int n0 = (j & 7) * 128, m0 = ((j >> 3) & 7) * 128, b = j >> 6;
    const ushort* Vb_ = Vp + (size_t)b * 1024 * 256;
    gemm_core(Vb_ + (size_t)m0 * 256, Vb_ + (size_t)n0 * 256, 256, As, Bs, acc);
    ushort* Eb = E + ((size_t)b << 20);
    const float sh = shift[b];
    EPI_COORDS
    #pragma unroll
    for (int i = 0; i < 4; ++i)
        #pragma unroll
        for (int r = 0; r < 4; ++r) {
            const int row = m0 + rb + i * 16 + r;
            float e[4];
            float s = 0.f;
            #pragma unroll
            for (int jj = 0; jj < 4; ++jj) {
                e[jj] = __expf(acc[i][jj][r] - sh);
                s += e[jj];
                Eb[(size_t)row * 1024 + n0 + cb + jj * 16] = f2b(e[jj]);
            }
            s += __shfl_xor(s, 1, 64);
            s += __shfl_xor(s, 2, 64);
            s += __shfl_xor(s, 4, 64);
            s += __shfl_xor(s, 8, 64);
            if ((lane & 15) == 0)
                atomicAdd(&Z[b * 1024 + row], s);
        }
}

// ---- k_trbs: VpZT[b][h][n] = Vp[b][n][h] / Z[b*1024+n]
__global__ __launch_bounds__(256) void k_trbs(const ushort* __restrict__ Vp,
                                              const float* __restrict__ Z,
                                              ushort* __restrict__ VpZT) {
    __shared__ ushort t[64][68];
    const int b = blockIdx.z;
    const ushort* ib = Vp + (size_t)b * 1024 * 256;
    ushort* ob = VpZT + (size_t)b * 256 * 1024;
    const int c0 = blockIdx.x * 64, r0 = blockIdx.y * 64;
    const int tid = threadIdx.x;
    #pragma unroll
    for (int i = 0; i < 4; ++i) {
        int r = (tid >> 4) + i * 16, c4 = (tid & 15) * 4;
        uint2 v = *(const uint2*)(ib + (size_t)(r0 + r) * 256 + c0 + c4);
        float iz = 1.0f / Z[b * 1024 + r0 + r];
        unsigned lo = f2b(b2f((ushort)(v.x & 0xffff)) * iz) |
                      ((unsigned)f2b(b2f((ushort)(v.x >> 16)) * iz) << 16);
        unsigned hi = f2b(b2f((ushort)(v.y & 0xffff)) * iz) |
                      ((unsigned)f2b(b2f((ushort)(v.y >> 16)) * iz) << 16);
        *(uint2*)&t[r][c4] = make_uint2(lo, hi);
    }
    __syncthreads();
    #pragma unroll
    for (int i = 0; i < 4; ++i) {
        int oc = (tid >> 4) + i * 16, r4 = (tid & 15) * 4;
        unsigned lo = t[r4][oc] | ((unsigned)t[r4 + 1][oc] << 16);
        unsigned hi = t[r4 + 2][oc] | ((unsigned)t[r4 + 3][oc] << 16);
        *(uint2*)(ob + (size_t)(c0 + oc) * 1024 + r0 + r4) = make_uint2(lo, hi);
    }
}

// ---- k_t12 (fused): per block: 128 rows m x full 256 cols.
// Phase 1: t1 = E[m-panel] @ VpZT^T (K=1024) -> LDS (XOR-swizzled 128x256 bf16)
// Phase 2: t2 = t1 @ WcT^T (K=256), B-frags direct from L2
// Epilogue: transpose via LDS, write t2T[b][h][m] coalesced.
// 512 threads = 8 waves (2 row x 4 col quadrants).  Grid 256, XCD-swizzled.
__global__ __launch_bounds__(512) void k_t12(const ushort* __restrict__ E,
                                             const ushort* __restrict__ VpZT,
                                             const ushort* __restrict__ WcT,
                                             ushort* __restrict__ t2T) {
    __shared__ char smem[65536];
    char* Asb = smem;            // 16 KB: 128 rows x 128 B  (phase 1)
    char* Bsb = smem + 16384;    // 32 KB: 256 rows x 128 B  (phase 1)
    // whole smem = t1buf [128 m][512 B] (phase 2 A), then tT [256 h][256 B]

    const int j = (blockIdx.x & 7) * 32 + (blockIdx.x >> 3);
    const int m0 = (j & 7) * 128;
    const int b = j >> 3;
    const ushort* Eb = E + ((size_t)b << 20) + (size_t)m0 * 1024;
    const ushort* Vz = VpZT + (size_t)b * 256 * 1024;
    const int tid = threadIdx.x;
    const int lane = tid & 63, wave = tid >> 6;
    const int l8 = lane >> 3, l7 = lane & 7;
    const int swz = (l7 ^ l8) << 4;

    const char* pa[2]; char* la[2];
    const char* pb[4]; char* lb[4];
    #pragma unroll
    for (int ii = 0; ii < 2; ++ii) {
        int r = wave * 16 + ii * 8 + l8;
        pa[ii] = (const char*)(Eb + (size_t)r * 1024) + swz;
        la[ii] = Asb + (wave * 16 + ii * 8) * 128;
    }
    #pragma unroll
    for (int ii = 0; ii < 4; ++ii) {
        int r = wave * 32 + ii * 8 + l8;
        pb[ii] = (const char*)(Vz + (size_t)r * 1024) + swz;
        lb[ii] = Bsb + (wave * 32 + ii * 8) * 128;
    }
    const int rr = lane & 15;
    const int kq = (lane >> 4) << 4;
    const int mask = (rr & 7) << 4;
    const int wr = (wave >> 2) * 64, wc = (wave & 3) * 64;
    f32x4 acc[4][4] = {};
    for (int k0 = 0; k0 < 1024; k0 += 64) {
        __syncthreads();
        #pragma unroll
        for (int ii = 0; ii < 2; ++ii) { gl16(pa[ii], la[ii]); pa[ii] += 128; }
        #pragma unroll
        for (int ii = 0; ii < 4; ++ii) { gl16(pb[ii], lb[ii]); pb[ii] += 128; }
        __syncthreads();
        #pragma unroll
        for (int ks = 0; ks < 2; ++ks) {
            const int cc = (ks * 64 + kq) ^ mask;
            bf16x8 av[4], bv[4];
            #pragma unroll
            for (int i = 0; i < 4; ++i) {
                av[i] = *(const bf16x8*)(Asb + (wr + i * 16 + rr) * 128 + cc);
                bv[i] = *(const bf16x8*)(Bsb + (wc + i * 16 + rr) * 128 + cc);
            }
            #pragma unroll
            for (int i = 0; i < 4; ++i)
                #pragma unroll
                for (int jj = 0; jj < 4; ++jj)
                    acc[i][jj] = __builtin_amdgcn_mfma_f32_16x16x32_bf16(av[i], bv[jj], acc[i][jj], 0, 0, 0);
        }
    }
    // epilogue 1: t1 -> smem [128 m][256 h] bf16, byte = m*512 + ((2h) ^ ((m&7)<<4))
    __syncthreads();
    const int rb = wr + (lane >> 4) * 4;
    const int cbh = wc + (lane & 15);
    #pragma unroll
    for (int i = 0; i < 4; ++i)
        #pragma unroll
        for (int jj = 0; jj < 4; ++jj) {
            int h = cbh + jj * 16;
            #pragma unroll
            for (int r = 0; r < 4; ++r) {
                int m = rb + i * 16 + r;
                *(ushort*)(smem + m * 512 + ((2 * h) ^ ((m & 7) << 4))) = f2b(acc[i][jj][r]);
            }
        }
    __syncthreads();
    // phase 2: t2 = t1 @ WcT^T, K=256
    f32x4 acc2[4][4] = {};
    #pragma unroll
    for (int k2 = 0; k2 < 4; ++k2) {
        #pragma unroll
        for (int ks = 0; ks < 2; ++ks) {
            const int cbyte = k2 * 128 + ks * 64 + kq;
            bf16x8 av[4], bv[4];
            #pragma unroll
            for (int i = 0; i < 4; ++i) {
                int m = wr + i * 16 + rr;
                av[i] = *(const bf16x8*)(smem + m * 512 + (cbyte ^ ((m & 7) << 4)));
                int h = wc + i * 16 + rr;
                bv[i] = *(const bf16x8*)((const char*)WcT + h * 512 + cbyte);
            }
            #pragma unroll
            for (int i = 0; i < 4; ++i)
                #pragma unroll
                for (int jj = 0; jj < 4; ++jj)
                    acc2[i][jj] = __builtin_amdgcn_mfma_f32_16x16x32_bf16(av[i], bv[jj], acc2[i][jj], 0, 0, 0);
        }
    }
    __syncthreads();
    // epilogue 2: tT[256 h][128 m] bf16, byte = h*256 + ((2m) ^ ((h&7)<<4))
    #pragma unroll
    for (int i = 0; i < 4; ++i)
        #pragma unroll
        for (int jj = 0; jj < 4; ++jj) {
            int h = cbh + jj * 16;
            int m = rb + i * 16;
            unsigned u0 = f2b(acc2[i][jj][0]) | ((unsigned)f2b(acc2[i][jj][1]) << 16);
            unsigned u1 = f2b(acc2[i][jj][2]) | ((unsigned)f2b(acc2[i][jj][3]) << 16);
            *(uint2*)(smem + h * 256 + ((2 * m) ^ ((h & 7) << 4))) = make_uint2(u0, u1);
        }
    __syncthreads();
    ushort* ob = t2T + (size_t)b * 256 * 1024 + m0;
    const int h = tid >> 1, mh = (tid & 1) * 64;
    #pragma unroll
    for (int i = 0; i < 8; ++i) {
        uint4 v = *(const uint4*)(smem + h * 256 + (((mh + i * 8) * 2) ^ ((h & 7) << 4)));
        *(uint4*)(ob + (size_t)h * 1024 + mh + i * 8) = v;
    }
}

// ---- k_O: out = relu((E_b @ t2T_b^T)/Z[m] + resv), fp32 out.  1-D grid 512, swizzled.
__global__ __launch_bounds__(256) void k_O(const ushort* __restrict__ E, const ushort* __restrict__ t2T,
                                           const ushort* __restrict__ resv, const float* __restrict__ Z,
                                           float* __restrict__ out) {
    __shared__ ushort As[128 * 64], Bs[128 * 64];
    f32x4 acc[4][4] = {};
    const int j = (blockIdx.x & 7) * 64 + (blockIdx.x >> 3);
    const int n0 = (j & 1) * 128, m0 = ((j >> 1) & 7) * 128, b = j >> 4;
    gemm_core(E + ((size_t)b << 20) + (size_t)m0 * 1024,
              t2T + (size_t)b * 256 * 1024 + (size_t)n0 * 1024, 1024, As, Bs, acc);
    EPI_COORDS
    #pragma unroll
    for (int i = 0; i < 4; ++i)
        #pragma unroll
        for (int jj = 0; jj < 4; ++jj)
            #pragma unroll
            for (int r = 0; r < 4; ++r) {
                int row = m0 + rb + i * 16 + r;
                float iz = 1.0f / Z[b * 1024 + row];
                size_t off = ((size_t)(b * 1024 + row)) * 256 + n0 + cb + jj * 16;
                out[off] = fmaxf(acc[i][jj][r] * iz + b2f(resv[off]), 0.0f);
            }
}

extern "C" void kernel_launch(void* const* d_in, const int* in_sizes, int n_in,
                              void* d_out, int out_size, void* d_ws, size_t ws_size,
                              hipStream_t stream) {
    const float* V     = (const float*)d_in[0];
    const float* alpha = (const float*)d_in[1];
    const float* WVw   = (const float*)d_in[2];
    const float* WVb   = (const float*)d_in[3];
    const float* Wc    = (const float*)d_in[4];
    const float* resw  = (const float*)d_in[5];
    const float* resb  = (const float*)d_in[6];
    float* out = (float*)d_out;

    char* W = (char*)d_ws;
    ushort* Vb   = (ushort*)(W);                         // 48 MB
    ushort* E    = (ushort*)(W + (48ull  << 20));        // 64 MB
    ushort* Vp   = (ushort*)(W + (112ull << 20));        // 16 MB
    ushort* resv = (ushort*)(W + (128ull << 20));        // 16 MB
    ushort* VpZT = (ushort*)(W + (144ull << 20));        // 16 MB
    ushort* t2T  = (ushort*)(W + (192ull << 20));        // 16 MB
    ushort* Wcat = (ushort*)(W + (208ull << 20));        // 768 KB
    ushort* WcT  = (ushort*)(W + (209ull << 20));        // 128 KB
    float*  gpart= (float*) (W + (210ull << 20));        // 1.5 MB (16 chunks)
    float*  g    = (float*) (W + (212ull << 20));        // 96 KB
    float*  gW   = (float*) (W + (212ull << 20) + (128u << 10)); // 32 KB
    float*  shv  = (float*) (W + (212ull << 20) + (256u << 10)); // 128 B
    float*  rn   = (float*) (W + (212ull << 20) + (512u << 10)); // 128 KB
    float*  Z    = (float*) (W + (213ull << 20));        // 128 KB

    hipMemsetAsync(Z, 0, 32768 * sizeof(float), stream);

    k_castmean<<<dim3(32, 16), 192, 0, stream>>>(V, Vb, gpart);
    k_gsum<<<96, 256, 0, stream>>>(gpart, g);
    k_gW<<<32, 256, 0, stream>>>(g, WVw, gW);
    k_castw<<<192, 256, 0, stream>>>(WVw, resw, Wcat);
    k_wct<<<dim3(4, 4), 256, 0, stream>>>(Wc, WcT);
    k_proj<<<1024, 256, 0, stream>>>(Vb, Wcat, WVb, resb, gW, alpha, Vp, resv);
    k_rownorm<<<8192, 256, 0, stream>>>(Vp, rn);
    k_shift<<<32, 256, 0, stream>>>(rn, shv);
    k_sim<<<2048, 256, 0, stream>>>(Vp, shv, E, Z);
    k_trbs<<<dim3(4, 16, 32), 256, 0, stream>>>(Vp, Z, VpZT);
    k_t12<<<256, 512, 0, stream>>>(E, VpZT, WcT, t2T);
    k_O<<<512, 256, 0, stream>>>(E, t2T, resv, Z, out);
}